// Round 13
// baseline (188.828 us; speedup 1.0000x reference)
//
#include <hip/hip_runtime.h>
#include <hip/hip_fp16.h>
#include <cstdint>
#include <cstddef>

#define D 128
#define XTS 72  // padded row stride (u16) for transposed tiles: 144B = 9*16B, bank-rotating
typedef unsigned short u16;
typedef short bf16x8 __attribute__((ext_vector_type(8)));
typedef float f32x4 __attribute__((ext_vector_type(4)));

// bf16 pack/unpack (RTNE)
__device__ __forceinline__ u16 f2b(float f) {
    uint32_t u = __float_as_uint(f);
    return (u16)((u + 0x7FFFu + ((u >> 16) & 1u)) >> 16);
}
__device__ __forceinline__ float b2f(u16 b) {
    return __uint_as_float(((uint32_t)b) << 16);
}

// XOR swizzle on bf16 k-index within a [rows][128] LDS tile (16B groups)
#define SWZ(r, k) ((k) ^ (((r) & 7) << 3))

// ---------------- K0: fold weights -> bf16 strips ----------------
__global__ void k_prep(const float* __restrict__ Wv, const float* __restrict__ Wg,
                       const float* __restrict__ bg, const float* __restrict__ Wl,
                       const float* __restrict__ bl,
                       u16* __restrict__ Bcatb, float* __restrict__ biasout)
{
    const int b = blockIdx.x;
    const int t = threadIdx.x; // 128
    if (b < 384) {
        const int strip = b >> 7, n = b & 127;
        float val;
        if (strip == 0) {
            float s = 0.f;
#pragma unroll 8
            for (int m = 0; m < D; ++m) s += Wv[t * D + m] * Wl[n * D + m];
            val = s;
        } else if (strip == 1) {
            val = Wl[n * D + t];
        } else {
            float s = 0.f;
#pragma unroll 8
            for (int m = 0; m < D; ++m) s += Wl[n * D + m] * Wg[m * D + t];
            val = 0.6f * s;
        }
        Bcatb[(size_t)b * D + t] = f2b(val);
    } else {
        float s = 0.f;
#pragma unroll 8
        for (int m = 0; m < D; ++m) s += bg[m] * Wl[t * D + m];
        biasout[t] = bl[t] + 0.6f * s;
    }
}

// zero cnt
__global__ void k_init(int* __restrict__ cnt, int M)
{
    const int i = blockIdx.x * 256 + threadIdx.x;
    if (i < M) cnt[i] = 0;
}

// histogram + record within-segment position
__global__ void k_hist(const int* __restrict__ dst, int* __restrict__ cnt,
                       int* __restrict__ epos, int E)
{
    const int e = blockIdx.x * 256 + threadIdx.x;
    if (e < E) epos[e] = atomicAdd(&cnt[dst[e]], 1);
}

// ---------------- hierarchical exclusive scan (+ dinv fused) ----------------
__global__ __launch_bounds__(1024) void k_scan1(const int* __restrict__ cnt,
                                                int* __restrict__ offs,
                                                int* __restrict__ bsum,
                                                float* __restrict__ dinv, int M)
{
    __shared__ int wsum[16];
    const int t = threadIdx.x, lane = t & 63, w = t >> 6;
    const int i = blockIdx.x * 1024 + t;
    const int v = (i < M) ? cnt[i] : 0;
    if (i < M) dinv[i] = rsqrtf((float)(v + 1)); // +1 self loop
    int s = v;
    for (int off = 1; off < 64; off <<= 1) {
        int n = __shfl_up(s, off);
        if (lane >= off) s += n;
    }
    if (lane == 63) wsum[w] = s;
    __syncthreads();
    if (w == 0) {
        int ss = (lane < 16) ? wsum[lane] : 0;
        for (int off = 1; off < 16; off <<= 1) {
            int n = __shfl_up(ss, off);
            if (lane >= off) ss += n;
        }
        if (lane < 16) wsum[lane] = ss;
    }
    __syncthreads();
    const int woff = (w == 0) ? 0 : wsum[w - 1];
    if (i < M) offs[i] = woff + s - v;
    if (t == 1023) bsum[blockIdx.x] = wsum[15];
}

__global__ void k_scanB(int* __restrict__ bsum, int nb)
{
    const int t = threadIdx.x;
    int v = (t < nb) ? bsum[t] : 0;
    int s = v;
    for (int off = 1; off < 64; off <<= 1) {
        int n = __shfl_up(s, off);
        if (t >= off) s += n;
    }
    if (t < nb) bsum[t] = s - v; // exclusive
}

__global__ void k_scan2(const int* __restrict__ bsum, int* __restrict__ offs, int M)
{
    const int i = blockIdx.x * 256 + threadIdx.x;
    if (i < M) offs[i] += bsum[i >> 10];
}

// fill CSR, atomic-free: payload = src(16b) | fp16(w)<<16
__global__ void k_fill(const int* __restrict__ src, const int* __restrict__ dst,
                       const int* __restrict__ epos,
                       const float* __restrict__ dinv,
                       const int* __restrict__ offs,
                       uint32_t* __restrict__ cpk, int E)
{
    const int e = blockIdx.x * 256 + threadIdx.x;
    if (e < E) {
        const int s = src[e], d = dst[e];
        const int pos = offs[d] + epos[e];
        const float w = dinv[s] * dinv[d];
        const u16 hb = __half_as_ushort(__float2half(w));
        cpk[pos] = (uint32_t)(u16)s | ((uint32_t)hb << 16);
    }
}

// ---------------- K-GRAM: split-K partials of G = X^T X + colsum(X) ----------------
__global__ __launch_bounds__(256) void k_gram(const float* __restrict__ x,
                                              float* __restrict__ part,
                                              float* __restrict__ pcs, int M)
{
    __shared__ u16 xT[D * XTS]; // xT[c][r], row stride 72
    const int t = threadIdx.x;
    const int P = (int)gridDim.x;
    const int chunk = (M + P - 1) / P;
    const int rbeg = blockIdx.x * chunk;
    const int rend = min(rbeg + chunk, M);
    const int lane = t & 63, w = t >> 6;
    const int fr = lane & 15, kg = lane >> 4;

    f32x4 acc[2][8] = {};
    float csacc = 0.f;

    for (int r0 = rbeg; r0 < rend; r0 += 64) {
#pragma unroll
        for (int p = 0; p < 8; ++p) {
            const int flat = t + 256 * p;   // 2048 float4 slots
            const int rr = flat & 63;       // row = lane within wave
            const int c4 = flat >> 6;       // col-group, fixed per wave
            const int gr = r0 + rr;
            float4 v = make_float4(0.f, 0.f, 0.f, 0.f);
            if (gr < rend) v = *(const float4*)(x + (size_t)gr * D + c4 * 4);
            u16* dst = xT + (c4 * 4) * XTS + rr;
            dst[0]       = f2b(v.x);
            dst[XTS]     = f2b(v.y);
            dst[2 * XTS] = f2b(v.z);
            dst[3 * XTS] = f2b(v.w);
        }
        __syncthreads();
#pragma unroll
        for (int ks = 0; ks < 2; ++ks) {
            const int rb = ks * 32 + kg * 8;
            bf16x8 a[2], b[8];
#pragma unroll
            for (int i = 0; i < 2; ++i) {
                const int m = w * 32 + 16 * i + fr;
                a[i] = *(const bf16x8*)(xT + m * XTS + rb);
            }
#pragma unroll
            for (int j = 0; j < 8; ++j) {
                const int n = 16 * j + fr;
                b[j] = *(const bf16x8*)(xT + n * XTS + rb);
            }
#pragma unroll
            for (int i = 0; i < 2; ++i)
#pragma unroll
                for (int j = 0; j < 8; ++j)
                    acc[i][j] = __builtin_amdgcn_mfma_f32_16x16x32_bf16(a[i], b[j], acc[i][j], 0, 0, 0);
        }
        // colsum of this tile (register-accumulated; no atomics)
        if (t < D) {
            const u16* col = xT + t * XTS;
#pragma unroll 16
            for (int r = 0; r < 64; ++r) csacc += b2f(col[r]);
        }
        __syncthreads();
    }
    float* pp = part + (size_t)blockIdx.x * (D * D);
#pragma unroll
    for (int i = 0; i < 2; ++i)
#pragma unroll
        for (int reg = 0; reg < 4; ++reg) {
            const int m = w * 32 + 16 * i + kg * 4 + reg;
#pragma unroll
            for (int j = 0; j < 8; ++j)
                pp[(size_t)m * D + 16 * j + fr] = acc[i][j][reg];
        }
    if (t < D) pcs[(size_t)blockIdx.x * D + t] = csacc;
}

// split-K reduce: blocks 0..63 reduce part -> Graw; blocks 64..71 reduce pcs -> csx
__global__ void k_redC(const float* __restrict__ part, float* __restrict__ Craw,
                       const float* __restrict__ pcs, float* __restrict__ csx, int P)
{
    if (blockIdx.x < 64) {
        const int e = blockIdx.x * 256 + threadIdx.x; // 16384
        float s0 = 0.f, s1 = 0.f, s2 = 0.f, s3 = 0.f,
              s4 = 0.f, s5 = 0.f, s6 = 0.f, s7 = 0.f;
        int p = 0;
        for (; p + 8 <= P; p += 8) {
            s0 += part[(size_t)(p + 0) * (D * D) + e];
            s1 += part[(size_t)(p + 1) * (D * D) + e];
            s2 += part[(size_t)(p + 2) * (D * D) + e];
            s3 += part[(size_t)(p + 3) * (D * D) + e];
            s4 += part[(size_t)(p + 4) * (D * D) + e];
            s5 += part[(size_t)(p + 5) * (D * D) + e];
            s6 += part[(size_t)(p + 6) * (D * D) + e];
            s7 += part[(size_t)(p + 7) * (D * D) + e];
        }
        for (; p < P; ++p) s0 += part[(size_t)p * (D * D) + e];
        Craw[e] = ((s0 + s1) + (s2 + s3)) + ((s4 + s5) + (s6 + s7));
    } else {
        __shared__ float red[16][16];
        const int pb = blockIdx.x - 64;         // 0..7
        const int cl = threadIdx.x & 15;        // col within group
        const int sl = threadIdx.x >> 4;        // slice 0..15
        const int col = pb * 16 + cl;
        float s = 0.f;
#pragma unroll 8
        for (int p = sl; p < P; p += 16) s += pcs[(size_t)p * D + col];
        red[sl][cl] = s;
        __syncthreads();
        if (sl == 0) {
            float tot = 0.f;
#pragma unroll
            for (int i = 0; i < 16; ++i) tot += red[i][cl];
            csx[col] = tot;
        }
    }
}

// per-wave 16x64 patch of a 128x128 GEMM (16 waves cover all)
__device__ __forceinline__ void gemm16x64(const u16* __restrict__ A,
                                          const u16* __restrict__ B,
                                          f32x4 acc[4], int rw, int cw,
                                          int fr, int kg)
{
#pragma unroll
    for (int ks = 0; ks < 4; ++ks) {
        const int kb = ks * 32 + kg * 8;
        const int r = rw + fr;
        const bf16x8 a = *(const bf16x8*)(A + r * D + SWZ(r, kb));
#pragma unroll
        for (int j = 0; j < 4; ++j) {
            const int n = cw + 16 * j + fr;
            const bf16x8 b = *(const bf16x8*)(B + n * D + SWZ(n, kb));
            acc[j] = __builtin_amdgcn_mfma_f32_16x16x32_bf16(a, b, acc[j], 0, 0, 0);
        }
    }
}

// ---------------- K-SMALL: all 128x128 algebra, 1024 threads (16 waves) ----------------
// traces -> inv; C = Wk^T G Av; C5 = Av + inv*Wq*C; xkq = inv*Wq*(Wk^T csx)
__global__ __launch_bounds__(1024) void k_small(const float* __restrict__ Graw,
                                                const float* __restrict__ csx_g,
                                                const float* __restrict__ Wq,
                                                const float* __restrict__ Wk,
                                                const u16* __restrict__ stripV,
                                                float* __restrict__ xkq,
                                                u16* __restrict__ C5b)
{
    __shared__ u16 Ga[D * D]; // G A-layout -> later Wq A-layout
    __shared__ u16 Bq[D * D]; // Wq B-layout -> later Av B-layout
    __shared__ u16 Bk[D * D]; // Wk B-layout -> later (C*inv) B-layout
    __shared__ u16 T2[D * D]; // H2^T A-layout
    __shared__ float csx[D];
    __shared__ float ksum[D];
    __shared__ float trsh[32];
    __shared__ float invS;
    const int t = threadIdx.x;
    const int lane = t & 63, w = t >> 6;       // 16 waves
    const int fr = lane & 15, kg = lane >> 4;
    const int rw = (w & 7) * 16, cw = (w >> 3) * 64;

    if (t < D) csx[t] = csx_g[t];
    // stage: Ga = G (A-layout, vectorized), Bq/Bk = Wq/Wk (B-layout = transpose)
#pragma unroll
    for (int p = 0; p < 4; ++p) {
        const int e4 = t + 1024 * p;  // 4096 float4 groups
        const int e = e4 * 4;
        const int i = e >> 7, m = e & 127;
        const float4 g = *(const float4*)(Graw + e);
        u16 gb[4] = {f2b(g.x), f2b(g.y), f2b(g.z), f2b(g.w)};
        *(uint2*)(Ga + i * D + SWZ(i, m)) = *(const uint2*)gb;
        const float4 q = *(const float4*)(Wq + e);
        const float4 k = *(const float4*)(Wk + e);
        Bq[(m + 0) * D + SWZ(m + 0, i)] = f2b(q.x);
        Bq[(m + 1) * D + SWZ(m + 1, i)] = f2b(q.y);
        Bq[(m + 2) * D + SWZ(m + 2, i)] = f2b(q.z);
        Bq[(m + 3) * D + SWZ(m + 3, i)] = f2b(q.w);
        Bk[(m + 0) * D + SWZ(m + 0, i)] = f2b(k.x);
        Bk[(m + 1) * D + SWZ(m + 1, i)] = f2b(k.y);
        Bk[(m + 2) * D + SWZ(m + 2, i)] = f2b(k.z);
        Bk[(m + 3) * D + SWZ(m + 3, i)] = f2b(k.w);
    }
    __syncthreads();

    // H2 = G @ Wk -> T2 = H2^T (A-layout); trace_k
    {
        f32x4 acc[4] = {};
        gemm16x64(Ga, Bk, acc, rw, cw, fr, kg);
        float tk = 0.f;
#pragma unroll
        for (int reg = 0; reg < 4; ++reg) {
            const int row = rw + kg * 4 + reg;
#pragma unroll
            for (int j = 0; j < 4; ++j) {
                const int col = cw + 16 * j + fr;
                const float h = acc[j][reg];
                T2[col * D + SWZ(col, row)] = f2b(h);
                tk += h * b2f(Bk[col * D + SWZ(col, row)]); // Wk[row][col]
            }
        }
        for (int off = 32; off > 0; off >>= 1) tk += __shfl_down(tk, off);
        if (lane == 0) trsh[w] = tk;
    }
    __syncthreads();
    // H1 = G @ Wq -> trace_q
    {
        f32x4 acc[4] = {};
        gemm16x64(Ga, Bq, acc, rw, cw, fr, kg);
        float tq = 0.f;
#pragma unroll
        for (int reg = 0; reg < 4; ++reg) {
            const int row = rw + kg * 4 + reg;
#pragma unroll
            for (int j = 0; j < 4; ++j) {
                const int col = cw + 16 * j + fr;
                tq += acc[j][reg] * b2f(Bq[col * D + SWZ(col, row)]);
            }
        }
        for (int off = 32; off > 0; off >>= 1) tq += __shfl_down(tq, off);
        if (lane == 0) trsh[16 + w] = tq;
    }
    __syncthreads();
    if (t == 0) {
        float sk = 0.f, sq = 0.f;
#pragma unroll
        for (int i = 0; i < 16; ++i) { sk += trsh[i]; sq += trsh[16 + i]; }
        invS = 1.0f / (sqrtf(sq) * sqrtf(sk) * 128.0f);
    }
    if (t < D) {
        float s = 0.f;
#pragma unroll 8
        for (int j = 0; j < D; ++j) s += csx[j] * Wk[j * D + t];
        ksum[t] = s;
    }
    // restage: Ga <- Wq (A-layout, vectorized), Bq <- Av (B-layout, from stripV bf16)
#pragma unroll
    for (int p = 0; p < 4; ++p) {
        const int e4 = t + 1024 * p;
        const int e = e4 * 4;
        const int i = e >> 7, m = e & 127;
        const float4 q = *(const float4*)(Wq + e);
        u16 qb[4] = {f2b(q.x), f2b(q.y), f2b(q.z), f2b(q.w)};
        *(uint2*)(Ga + i * D + SWZ(i, m)) = *(const uint2*)qb;
    }
#pragma unroll
    for (int p = 0; p < 2; ++p) {
        const int e8 = (t + 1024 * p) * 8;
        const int n = e8 >> 7, i0 = e8 & 127;
        *(uint4*)(Bq + n * D + SWZ(n, i0)) = *(const uint4*)(stripV + n * D + i0);
    }
    __syncthreads();
    // C = T2(H2^T) @ Bq(Av) -> Bk <- (C*inv) B-layout; xkq
    {
        f32x4 acc[4] = {};
        gemm16x64(T2, Bq, acc, rw, cw, fr, kg);
        const float inv = invS;
#pragma unroll
        for (int reg = 0; reg < 4; ++reg) {
            const int m = rw + kg * 4 + reg;
#pragma unroll
            for (int j = 0; j < 4; ++j) {
                const int n = cw + 16 * j + fr;
                Bk[n * D + SWZ(n, m)] = f2b(acc[j][reg] * inv);
            }
        }
    }
    if (t < D) {
        float s = 0.f;
        const float inv = invS;
#pragma unroll 8
        for (int o = 0; o < D; ++o) s += Wq[t * D + o] * ksum[o];
        xkq[t] = s * inv;
    }
    __syncthreads();
    // C4 = Ga(Wq) @ Bk(C*inv); C5b[n][i] = Av[i][n] + C4[i][n]
    {
        f32x4 acc[4] = {};
        gemm16x64(Ga, Bk, acc, rw, cw, fr, kg);
#pragma unroll
        for (int reg = 0; reg < 4; ++reg) {
            const int r = rw + kg * 4 + reg; // C4 row i-index
#pragma unroll
            for (int j = 0; j < 4; ++j) {
                const int n = cw + 16 * j + fr;
                C5b[n * D + r] = f2b(b2f(stripV[n * D + r]) + acc[j][reg]);
            }
        }
    }
}

// ---------------- K-U: u = x @ stripU (single-matrix MFMA GEMM) ----------------
__global__ __launch_bounds__(256) void k_ugemm(const float* __restrict__ x,
                                               const u16* __restrict__ stripU,
                                               u16* __restrict__ ub, int M)
{
    __shared__ u16 As[64 * D];
    __shared__ u16 Bs[64 * D];
    const int t = threadIdx.x;
    const int row0 = blockIdx.x * 64;

#pragma unroll
    for (int p = 0; p < 4; ++p) {
        const int flat = t + 256 * p;
        const int r = flat >> 4, kg = flat & 15;
        int gr = row0 + r; if (gr > M - 1) gr = M - 1;
        const float4 f0 = *(const float4*)(x + (size_t)gr * D + kg * 8);
        const float4 f1 = *(const float4*)(x + (size_t)gr * D + kg * 8 + 4);
        u16 rr[8] = {f2b(f0.x), f2b(f0.y), f2b(f0.z), f2b(f0.w),
                     f2b(f1.x), f2b(f1.y), f2b(f1.z), f2b(f1.w)};
        *(uint4*)(As + r * D + SWZ(r, kg * 8)) = *(const uint4*)rr;
    }
#pragma unroll
    for (int p = 0; p < 4; ++p) {
        const int flat = t + 256 * p;
        const int r = flat >> 4, kg = flat & 15;
        const uint4 v = *(const uint4*)(stripU + (size_t)r * D + kg * 8);
        *(uint4*)(Bs + r * D + SWZ(r, kg * 8)) = v;
    }
    __syncthreads();

    const int lane = t & 63, w = t >> 6;
    const int wr = (w >> 1) * 32, wc = (w & 1) * 32;
    const int fr = lane & 15, kg2 = lane >> 4;

#pragma unroll
    for (int h = 0; h < 2; ++h) {
        f32x4 acc[2][2] = {};
#pragma unroll
        for (int ks = 0; ks < 4; ++ks) {
            const int kb = ks * 32 + kg2 * 8;
            bf16x8 a[2], b[2];
#pragma unroll
            for (int i = 0; i < 2; ++i) {
                const int r = wr + 16 * i + fr;
                a[i] = *(const bf16x8*)(As + r * D + SWZ(r, kb));
            }
#pragma unroll
            for (int j = 0; j < 2; ++j) {
                const int r = wc + 16 * j + fr;
                b[j] = *(const bf16x8*)(Bs + r * D + SWZ(r, kb));
            }
#pragma unroll
            for (int i = 0; i < 2; ++i)
#pragma unroll
                for (int j = 0; j < 2; ++j)
                    acc[i][j] = __builtin_amdgcn_mfma_f32_16x16x32_bf16(a[i], b[j], acc[i][j], 0, 0, 0);
        }
        __syncthreads();
        if (h == 0) {
#pragma unroll
            for (int p = 0; p < 4; ++p) {
                const int flat = t + 256 * p;
                const int r = flat >> 4, kg = flat & 15;
                const uint4 v = *(const uint4*)(stripU + (size_t)(64 + r) * D + kg * 8);
                *(uint4*)(Bs + r * D + SWZ(r, kg * 8)) = v;
            }
        }
        const int col0 = h * 64;
#pragma unroll
        for (int i = 0; i < 2; ++i) {
#pragma unroll
            for (int reg = 0; reg < 4; ++reg) {
                const int r = row0 + wr + 16 * i + kg2 * 4 + reg;
                if (r < M) {
#pragma unroll
                    for (int j = 0; j < 2; ++j) {
                        const int col = col0 + wc + 16 * j + fr;
                        ub[(size_t)r * D + col] = f2b(acc[i][j][reg]);
                    }
                }
            }
        }
        if (h == 0) __syncthreads();
    }
}

// ---------------- K-FINAL: out = rc*(x@C5) + 0.24*(x@Wl^T) + bias + sc*u ----------------
__global__ __launch_bounds__(256) void k_final(const float* __restrict__ x,
                                               const u16* __restrict__ C5b,
                                               const u16* __restrict__ stripL,
                                               const u16* __restrict__ ub,
                                               const int* __restrict__ cnt,
                                               const float* __restrict__ xkq,
                                               const float* __restrict__ biasout,
                                               float* __restrict__ out, int M)
{
    __shared__ u16 As[64 * D];
    __shared__ u16 Bs[64 * D];
    __shared__ float scaleS[64];
    const int t = threadIdx.x;
    const int row0 = blockIdx.x * 64;
    const int half = blockIdx.y;

#pragma unroll
    for (int p = 0; p < 4; ++p) {
        const int flat = t + 256 * p;
        const int r = flat >> 4, kg = flat & 15;
        int gr = row0 + r; if (gr > M - 1) gr = M - 1;
        const float4 f0 = *(const float4*)(x + (size_t)gr * D + kg * 8);
        const float4 f1 = *(const float4*)(x + (size_t)gr * D + kg * 8 + 4);
        u16 rr[8] = {f2b(f0.x), f2b(f0.y), f2b(f0.z), f2b(f0.w),
                     f2b(f1.x), f2b(f1.y), f2b(f1.z), f2b(f1.w)};
        *(uint4*)(As + r * D + SWZ(r, kg * 8)) = *(const uint4*)rr;
    }
#pragma unroll
    for (int p = 0; p < 4; ++p) {
        const int flat = t + 256 * p;
        const int r = flat >> 4, kg = flat & 15;
        const uint4 v = *(const uint4*)(C5b + (size_t)(half * 64 + r) * D + kg * 8);
        *(uint4*)(Bs + r * D + SWZ(r, kg * 8)) = v;
    }
    __syncthreads();

    // rc: qk_r = x_r . xkq
    {
        const int rr = t >> 2, qq = t & 3;
        float s = 0.f;
#pragma unroll
        for (int i = 0; i < 4; ++i) {
            const int kk = qq * 32 + i * 8;
            const bf16x8 a = *(const bf16x8*)(As + rr * D + SWZ(rr, kk));
            const u16* ap = (const u16*)&a;
#pragma unroll
            for (int jj = 0; jj < 8; ++jj) s += b2f(ap[jj]) * xkq[kk + jj];
        }
        s += __shfl_xor(s, 1);
        s += __shfl_xor(s, 2);
        if (qq == 0) scaleS[rr] = 0.16f / (1.0f + s);
    }

    const int lane = t & 63, w = t >> 6;
    const int wr = (w >> 1) * 32, wc = (w & 1) * 32;
    const int fr = lane & 15, kg2 = lane >> 4;

    f32x4 acc1[2][2] = {};
#pragma unroll
    for (int ks = 0; ks < 4; ++ks) {
        const int kb = ks * 32 + kg2 * 8;
        bf16x8 a[2], b[2];
#pragma unroll
        for (int i = 0; i < 2; ++i) {
            const int r = wr + 16 * i + fr;
            a[i] = *(const bf16x8*)(As + r * D + SWZ(r, kb));
        }
#pragma unroll
        for (int j = 0; j < 2; ++j) {
            const int r = wc + 16 * j + fr;
            b[j] = *(const bf16x8*)(Bs + r * D + SWZ(r, kb));
        }
#pragma unroll
        for (int i = 0; i < 2; ++i)
#pragma unroll
            for (int j = 0; j < 2; ++j)
                acc1[i][j] = __builtin_amdgcn_mfma_f32_16x16x32_bf16(a[i], b[j], acc1[i][j], 0, 0, 0);
    }
    __syncthreads();
    // restage Bs <- stripL rows (half*64 ..)
#pragma unroll
    for (int p = 0; p < 4; ++p) {
        const int flat = t + 256 * p;
        const int r = flat >> 4, kg = flat & 15;
        const uint4 v = *(const uint4*)(stripL + (size_t)(half * 64 + r) * D + kg * 8);
        *(uint4*)(Bs + r * D + SWZ(r, kg * 8)) = v;
    }
    __syncthreads();

    f32x4 acc2[2][2] = {};
#pragma unroll
    for (int ks = 0; ks < 4; ++ks) {
        const int kb = ks * 32 + kg2 * 8;
        bf16x8 a[2], b[2];
#pragma unroll
        for (int i = 0; i < 2; ++i) {
            const int r = wr + 16 * i + fr;
            a[i] = *(const bf16x8*)(As + r * D + SWZ(r, kb));
        }
#pragma unroll
        for (int j = 0; j < 2; ++j) {
            const int r = wc + 16 * j + fr;
            b[j] = *(const bf16x8*)(Bs + r * D + SWZ(r, kb));
        }
#pragma unroll
        for (int i = 0; i < 2; ++i)
#pragma unroll
            for (int j = 0; j < 2; ++j)
                acc2[i][j] = __builtin_amdgcn_mfma_f32_16x16x32_bf16(a[i], b[j], acc2[i][j], 0, 0, 0);
    }

#pragma unroll
    for (int i = 0; i < 2; ++i) {
#pragma unroll
        for (int reg = 0; reg < 4; ++reg) {
            const int rloc = wr + 16 * i + kg2 * 4 + reg;
            const int r = row0 + rloc;
            if (r < M) {
                const float rc = scaleS[rloc];
                const float sc = 1.0f / (float)(cnt[r] + 1);
#pragma unroll
                for (int j = 0; j < 2; ++j) {
                    const int c = half * 64 + wc + 16 * j + fr;
                    const size_t idx = (size_t)r * D + c;
                    out[idx] = rc * acc1[i][j][reg] + 0.24f * acc2[i][j][reg]
                             + biasout[c] + sc * b2f(ub[idx]);
                }
            }
        }
    }
}

// ---------------- K5: wave-cooperative CSR gather (packed payload) ----------------
__global__ __launch_bounds__(256) void k_gather(const int* __restrict__ offs,
                                                const int* __restrict__ cnt,
                                                const uint32_t* __restrict__ cpk,
                                                const u16* __restrict__ ub,
                                                float* __restrict__ out, int M)
{
    const int t = threadIdx.x;
    const int w = t >> 6, lane = t & 63;
    const int d = blockIdx.x * 4 + w;
    if (d >= M) return;
    const int g = lane >> 4, sub = lane & 15;
    const int beg = offs[d];
    const int n = cnt[d];
    if (n == 0) return;
    const int end = beg + n;
    float acc[8] = {};
    for (int j0 = beg; j0 < end; j0 += 8) {
        const int j1 = j0 + g, j2 = j0 + 4 + g;
        int s1 = 0, s2 = 0;
        float w1 = 0.f, w2 = 0.f;
        if (j1 < end) {
            const uint32_t p = cpk[j1];
            s1 = (int)(p & 0xFFFFu);
            w1 = __half2float(__ushort_as_half((u16)(p >> 16)));
        }
        if (j2 < end) {
            const uint32_t p = cpk[j2];
            s2 = (int)(p & 0xFFFFu);
            w2 = __half2float(__ushort_as_half((u16)(p >> 16)));
        }
        const uint4 r1 = *(const uint4*)(ub + (size_t)s1 * D + sub * 8);
        const uint4 r2 = *(const uint4*)(ub + (size_t)s2 * D + sub * 8);
        const u16* p1 = (const u16*)&r1;
        const u16* p2 = (const u16*)&r2;
#pragma unroll
        for (int i = 0; i < 8; ++i) acc[i] += w1 * b2f(p1[i]) + w2 * b2f(p2[i]);
    }
#pragma unroll
    for (int i = 0; i < 8; ++i) {
        acc[i] += __shfl_xor(acc[i], 16);
        acc[i] += __shfl_xor(acc[i], 32);
    }
    if (g == 0) {
        float* o = out + (size_t)d * D + sub * 8;
        float4 o0 = *(float4*)o, o1 = *(float4*)(o + 4);
        o0.x += acc[0]; o0.y += acc[1]; o0.z += acc[2]; o0.w += acc[3];
        o1.x += acc[4]; o1.y += acc[5]; o1.z += acc[6]; o1.w += acc[7];
        *(float4*)o = o0; *(float4*)(o + 4) = o1;
    }
}

extern "C" void kernel_launch(void* const* d_in, const int* in_sizes, int n_in,
                              void* d_out, int out_size, void* d_ws, size_t ws_size,
                              hipStream_t stream)
{
    const float* x  = (const float*)d_in[0];
    const int*   ei = (const int*)d_in[1];
    const float* Wq = (const float*)d_in[2];
    const float* Wk = (const float*)d_in[3];
    const float* Wv = (const float*)d_in[4];
    const float* Wg = (const float*)d_in[5];
    const float* bg = (const float*)d_in[6];
    const float* Wl = (const float*)d_in[7];
    const float* bl = (const float*)d_in[8];

    const int M = in_sizes[0] / D;
    const int E = in_sizes[1] / 2;
    const size_t NQ = (size_t)M * D;
    const int P = 512;
    const int NBG = (M + 63) / 64;
    const int NB = (M + 1023) / 1024;

    char* base = (char*)d_ws;
    auto alloc = [&](size_t bytes) -> char* {
        char* p = base; base += (bytes + 63) & ~(size_t)63; return p;
    };
    float* part    = (float*)alloc((size_t)P * D * D * 4);
    float* Graw    = (float*)alloc(D * D * 4);
    float* pcs     = (float*)alloc((size_t)P * D * 4);
    float* csx     = (float*)alloc(D * 4);
    float* dinv    = (float*)alloc((size_t)M * 4);
    float* xkq     = (float*)alloc(D * 4);
    float* biasout = (float*)alloc(D * 4);
    int*   cnt     = (int*)alloc((size_t)M * 4);
    int*   offs    = (int*)alloc((size_t)M * 4);
    int*   bsum    = (int*)alloc(64 * 4);
    int*   epos    = (int*)alloc((size_t)E * 4);
    uint32_t* cpk  = (uint32_t*)alloc((size_t)E * 4);
    u16*   Bcatb   = (u16*)alloc((size_t)384 * D * 2);
    u16*   C5b     = (u16*)alloc(D * D * 2);
    u16*   ub      = (u16*)alloc(NQ * 2);

    const u16* stripV = Bcatb;
    const u16* stripL = Bcatb + D * D;
    const u16* stripU = Bcatb + 2 * D * D;

    float* out = (float*)d_out;

    // weights + CSR build
    k_prep<<<dim3(385), dim3(128), 0, stream>>>(Wv, Wg, bg, Wl, bl, Bcatb, biasout);
    k_init<<<(M + 255) / 256, 256, 0, stream>>>(cnt, M);
    k_hist<<<(E + 255) / 256, 256, 0, stream>>>(ei + E, cnt, epos, E);
    k_scan1<<<NB, 1024, 0, stream>>>(cnt, offs, bsum, dinv, M);
    k_scanB<<<1, 64, 0, stream>>>(bsum, NB);
    k_scan2<<<(M + 255) / 256, 256, 0, stream>>>(bsum, offs, M);
    k_fill<<<(E + 255) / 256, 256, 0, stream>>>(ei, ei + E, epos, dinv, offs, cpk, E);

    // dense chain (Gram restructure)
    k_gram<<<P, 256, 0, stream>>>(x, part, pcs, M);
    k_redC<<<72, 256, 0, stream>>>(part, Graw, pcs, csx, P);
    k_small<<<1, 1024, 0, stream>>>(Graw, csx, Wq, Wk, stripV, xkq, C5b);
    k_ugemm<<<NBG, 256, 0, stream>>>(x, stripU, ub, M);
    k_final<<<dim3(NBG, 2), 256, 0, stream>>>(x, C5b, stripL, ub, cnt, xkq, biasout, out, M);
    k_gather<<<(M + 3) / 4, 256, 0, stream>>>(offs, cnt, cpk, ub, out, M);
}

// Round 14
// 186.036 us; speedup vs baseline: 1.0150x; 1.0150x over previous
//
#include <hip/hip_runtime.h>
#include <hip/hip_fp16.h>
#include <cstdint>
#include <cstddef>

#define D 128
#define XTS 72  // padded row stride (u16) for transposed tiles: 144B = 9*16B, bank-rotating
typedef unsigned short u16;
typedef short bf16x8 __attribute__((ext_vector_type(8)));
typedef float f32x4 __attribute__((ext_vector_type(4)));

// bf16 pack/unpack (RTNE)
__device__ __forceinline__ u16 f2b(float f) {
    uint32_t u = __float_as_uint(f);
    return (u16)((u + 0x7FFFu + ((u >> 16) & 1u)) >> 16);
}
__device__ __forceinline__ float b2f(u16 b) {
    return __uint_as_float(((uint32_t)b) << 16);
}

// XOR swizzle on bf16 k-index within a [rows][128] LDS tile (16B groups)
#define SWZ(r, k) ((k) ^ (((r) & 7) << 3))

// ---------------- K0: fold weights -> bf16 strips ----------------
__global__ void k_prep(const float* __restrict__ Wv, const float* __restrict__ Wg,
                       const float* __restrict__ bg, const float* __restrict__ Wl,
                       const float* __restrict__ bl,
                       u16* __restrict__ Bcatb, float* __restrict__ biasout)
{
    const int b = blockIdx.x;
    const int t = threadIdx.x; // 128
    if (b < 384) {
        const int strip = b >> 7, n = b & 127;
        float val;
        if (strip == 0) {
            float s = 0.f;
#pragma unroll 8
            for (int m = 0; m < D; ++m) s += Wv[t * D + m] * Wl[n * D + m];
            val = s;
        } else if (strip == 1) {
            val = Wl[n * D + t];
        } else {
            float s = 0.f;
#pragma unroll 8
            for (int m = 0; m < D; ++m) s += Wl[n * D + m] * Wg[m * D + t];
            val = 0.6f * s;
        }
        Bcatb[(size_t)b * D + t] = f2b(val);
    } else {
        float s = 0.f;
#pragma unroll 8
        for (int m = 0; m < D; ++m) s += bg[m] * Wl[t * D + m];
        biasout[t] = bl[t] + 0.6f * s;
    }
}

// zero cnt
__global__ void k_init(int* __restrict__ cnt, int M)
{
    const int i = blockIdx.x * 256 + threadIdx.x;
    if (i < M) cnt[i] = 0;
}

// histogram + record within-segment position
__global__ void k_hist(const int* __restrict__ dst, int* __restrict__ cnt,
                       int* __restrict__ epos, int E)
{
    const int e = blockIdx.x * 256 + threadIdx.x;
    if (e < E) epos[e] = atomicAdd(&cnt[dst[e]], 1);
}

// ---------------- hierarchical exclusive scan (+ dinv fused) ----------------
__global__ __launch_bounds__(1024) void k_scan1(const int* __restrict__ cnt,
                                                int* __restrict__ offs,
                                                int* __restrict__ bsum,
                                                float* __restrict__ dinv, int M)
{
    __shared__ int wsum[16];
    const int t = threadIdx.x, lane = t & 63, w = t >> 6;
    const int i = blockIdx.x * 1024 + t;
    const int v = (i < M) ? cnt[i] : 0;
    if (i < M) dinv[i] = rsqrtf((float)(v + 1)); // +1 self loop
    int s = v;
    for (int off = 1; off < 64; off <<= 1) {
        int n = __shfl_up(s, off);
        if (lane >= off) s += n;
    }
    if (lane == 63) wsum[w] = s;
    __syncthreads();
    if (w == 0) {
        int ss = (lane < 16) ? wsum[lane] : 0;
        for (int off = 1; off < 16; off <<= 1) {
            int n = __shfl_up(ss, off);
            if (lane >= off) ss += n;
        }
        if (lane < 16) wsum[lane] = ss;
    }
    __syncthreads();
    const int woff = (w == 0) ? 0 : wsum[w - 1];
    if (i < M) offs[i] = woff + s - v;
    if (t == 1023) bsum[blockIdx.x] = wsum[15];
}

__global__ void k_scanB(int* __restrict__ bsum, int nb)
{
    const int t = threadIdx.x;
    int v = (t < nb) ? bsum[t] : 0;
    int s = v;
    for (int off = 1; off < 64; off <<= 1) {
        int n = __shfl_up(s, off);
        if (t >= off) s += n;
    }
    if (t < nb) bsum[t] = s - v; // exclusive
}

__global__ void k_scan2(const int* __restrict__ bsum, int* __restrict__ offs, int M)
{
    const int i = blockIdx.x * 256 + threadIdx.x;
    if (i < M) offs[i] += bsum[i >> 10];
}

// fill CSR, atomic-free: payload = src(16b) | fp16(w)<<16
__global__ void k_fill(const int* __restrict__ src, const int* __restrict__ dst,
                       const int* __restrict__ epos,
                       const float* __restrict__ dinv,
                       const int* __restrict__ offs,
                       uint32_t* __restrict__ cpk, int E)
{
    const int e = blockIdx.x * 256 + threadIdx.x;
    if (e < E) {
        const int s = src[e], d = dst[e];
        const int pos = offs[d] + epos[e];
        const float w = dinv[s] * dinv[d];
        const u16 hb = __half_as_ushort(__float2half(w));
        cpk[pos] = (uint32_t)(u16)s | ((uint32_t)hb << 16);
    }
}

// ---------------- K-GRAM: split-K partials of G = X^T X + colsum(X) ----------------
// bf16 partials (f32 accumulate, bf16 store) to halve partial traffic.
__global__ __launch_bounds__(256) void k_gram(const float* __restrict__ x,
                                              u16* __restrict__ part,
                                              float* __restrict__ pcs, int M)
{
    __shared__ u16 xT[D * XTS]; // xT[c][r], row stride 72
    const int t = threadIdx.x;
    const int P = (int)gridDim.x;
    const int chunk = (M + P - 1) / P;
    const int rbeg = blockIdx.x * chunk;
    const int rend = min(rbeg + chunk, M);
    const int lane = t & 63, w = t >> 6;
    const int fr = lane & 15, kg = lane >> 4;

    f32x4 acc[2][8] = {};
    float csacc = 0.f;

    for (int r0 = rbeg; r0 < rend; r0 += 64) {
#pragma unroll
        for (int p = 0; p < 8; ++p) {
            const int flat = t + 256 * p;   // 2048 float4 slots
            const int rr = flat & 63;       // row = lane within wave
            const int c4 = flat >> 6;       // col-group, fixed per wave
            const int gr = r0 + rr;
            float4 v = make_float4(0.f, 0.f, 0.f, 0.f);
            if (gr < rend) v = *(const float4*)(x + (size_t)gr * D + c4 * 4);
            u16* dst = xT + (c4 * 4) * XTS + rr;
            dst[0]       = f2b(v.x);
            dst[XTS]     = f2b(v.y);
            dst[2 * XTS] = f2b(v.z);
            dst[3 * XTS] = f2b(v.w);
        }
        __syncthreads();
#pragma unroll
        for (int ks = 0; ks < 2; ++ks) {
            const int rb = ks * 32 + kg * 8;
            bf16x8 a[2], b[8];
#pragma unroll
            for (int i = 0; i < 2; ++i) {
                const int m = w * 32 + 16 * i + fr;
                a[i] = *(const bf16x8*)(xT + m * XTS + rb);
            }
#pragma unroll
            for (int j = 0; j < 8; ++j) {
                const int n = 16 * j + fr;
                b[j] = *(const bf16x8*)(xT + n * XTS + rb);
            }
#pragma unroll
            for (int i = 0; i < 2; ++i)
#pragma unroll
                for (int j = 0; j < 8; ++j)
                    acc[i][j] = __builtin_amdgcn_mfma_f32_16x16x32_bf16(a[i], b[j], acc[i][j], 0, 0, 0);
        }
        // colsum of this tile (register-accumulated; no atomics)
        if (t < D) {
            const u16* col = xT + t * XTS;
#pragma unroll 16
            for (int r = 0; r < 64; ++r) csacc += b2f(col[r]);
        }
        __syncthreads();
    }
    u16* pp = part + (size_t)blockIdx.x * (D * D);
#pragma unroll
    for (int i = 0; i < 2; ++i)
#pragma unroll
        for (int reg = 0; reg < 4; ++reg) {
            const int m = w * 32 + 16 * i + kg * 4 + reg;
#pragma unroll
            for (int j = 0; j < 8; ++j)
                pp[(size_t)m * D + 16 * j + fr] = f2b(acc[i][j][reg]);
        }
    if (t < D) pcs[(size_t)blockIdx.x * D + t] = csacc;
}

// split-K reduce: blocks 0..63 reduce part (bf16) -> Graw; blocks 64..71 reduce pcs -> csx
__global__ void k_redC(const u16* __restrict__ part, float* __restrict__ Craw,
                       const float* __restrict__ pcs, float* __restrict__ csx, int P)
{
    if (blockIdx.x < 64) {
        const int e = blockIdx.x * 256 + threadIdx.x; // 16384
        float s0 = 0.f, s1 = 0.f, s2 = 0.f, s3 = 0.f,
              s4 = 0.f, s5 = 0.f, s6 = 0.f, s7 = 0.f;
        int p = 0;
        for (; p + 8 <= P; p += 8) {
            s0 += b2f(part[(size_t)(p + 0) * (D * D) + e]);
            s1 += b2f(part[(size_t)(p + 1) * (D * D) + e]);
            s2 += b2f(part[(size_t)(p + 2) * (D * D) + e]);
            s3 += b2f(part[(size_t)(p + 3) * (D * D) + e]);
            s4 += b2f(part[(size_t)(p + 4) * (D * D) + e]);
            s5 += b2f(part[(size_t)(p + 5) * (D * D) + e]);
            s6 += b2f(part[(size_t)(p + 6) * (D * D) + e]);
            s7 += b2f(part[(size_t)(p + 7) * (D * D) + e]);
        }
        for (; p < P; ++p) s0 += b2f(part[(size_t)p * (D * D) + e]);
        Craw[e] = ((s0 + s1) + (s2 + s3)) + ((s4 + s5) + (s6 + s7));
    } else {
        __shared__ float red[16][16];
        const int pb = blockIdx.x - 64;         // 0..7
        const int cl = threadIdx.x & 15;        // col within group
        const int sl = threadIdx.x >> 4;        // slice 0..15
        const int col = pb * 16 + cl;
        float s = 0.f;
#pragma unroll 8
        for (int p = sl; p < P; p += 16) s += pcs[(size_t)p * D + col];
        red[sl][cl] = s;
        __syncthreads();
        if (sl == 0) {
            float tot = 0.f;
#pragma unroll
            for (int i = 0; i < 16; ++i) tot += red[i][cl];
            csx[col] = tot;
        }
    }
}

// per-wave 16x64 patch of a 128x128 GEMM (16 waves cover all)
__device__ __forceinline__ void gemm16x64(const u16* __restrict__ A,
                                          const u16* __restrict__ B,
                                          f32x4 acc[4], int rw, int cw,
                                          int fr, int kg)
{
#pragma unroll
    for (int ks = 0; ks < 4; ++ks) {
        const int kb = ks * 32 + kg * 8;
        const int r = rw + fr;
        const bf16x8 a = *(const bf16x8*)(A + r * D + SWZ(r, kb));
#pragma unroll
        for (int j = 0; j < 4; ++j) {
            const int n = cw + 16 * j + fr;
            const bf16x8 b = *(const bf16x8*)(B + n * D + SWZ(n, kb));
            acc[j] = __builtin_amdgcn_mfma_f32_16x16x32_bf16(a, b, acc[j], 0, 0, 0);
        }
    }
}

// ---------------- K-SMALL: all 128x128 algebra, 1024 threads (16 waves) ----------------
__global__ __launch_bounds__(1024) void k_small(const float* __restrict__ Graw,
                                                const float* __restrict__ csx_g,
                                                const float* __restrict__ Wq,
                                                const float* __restrict__ Wk,
                                                const u16* __restrict__ stripV,
                                                float* __restrict__ xkq,
                                                u16* __restrict__ C5b)
{
    __shared__ u16 Ga[D * D]; // G A-layout -> later Wq A-layout
    __shared__ u16 Bq[D * D]; // Wq B-layout -> later Av B-layout
    __shared__ u16 Bk[D * D]; // Wk B-layout -> later (C*inv) B-layout
    __shared__ u16 T2[D * D]; // H2^T A-layout
    __shared__ float csx[D];
    __shared__ float ksum[D];
    __shared__ float trsh[32];
    __shared__ float invS;
    const int t = threadIdx.x;
    const int lane = t & 63, w = t >> 6;       // 16 waves
    const int fr = lane & 15, kg = lane >> 4;
    const int rw = (w & 7) * 16, cw = (w >> 3) * 64;

    if (t < D) csx[t] = csx_g[t];
    // stage: Ga = G (A-layout, vectorized), Bq/Bk = Wq/Wk (B-layout = transpose)
#pragma unroll
    for (int p = 0; p < 4; ++p) {
        const int e4 = t + 1024 * p;  // 4096 float4 groups
        const int e = e4 * 4;
        const int i = e >> 7, m = e & 127;
        const float4 g = *(const float4*)(Graw + e);
        u16 gb[4] = {f2b(g.x), f2b(g.y), f2b(g.z), f2b(g.w)};
        *(uint2*)(Ga + i * D + SWZ(i, m)) = *(const uint2*)gb;
        const float4 q = *(const float4*)(Wq + e);
        const float4 k = *(const float4*)(Wk + e);
        Bq[(m + 0) * D + SWZ(m + 0, i)] = f2b(q.x);
        Bq[(m + 1) * D + SWZ(m + 1, i)] = f2b(q.y);
        Bq[(m + 2) * D + SWZ(m + 2, i)] = f2b(q.z);
        Bq[(m + 3) * D + SWZ(m + 3, i)] = f2b(q.w);
        Bk[(m + 0) * D + SWZ(m + 0, i)] = f2b(k.x);
        Bk[(m + 1) * D + SWZ(m + 1, i)] = f2b(k.y);
        Bk[(m + 2) * D + SWZ(m + 2, i)] = f2b(k.z);
        Bk[(m + 3) * D + SWZ(m + 3, i)] = f2b(k.w);
    }
    __syncthreads();

    // H2 = G @ Wk -> T2 = H2^T (A-layout); trace_k
    {
        f32x4 acc[4] = {};
        gemm16x64(Ga, Bk, acc, rw, cw, fr, kg);
        float tk = 0.f;
#pragma unroll
        for (int reg = 0; reg < 4; ++reg) {
            const int row = rw + kg * 4 + reg;
#pragma unroll
            for (int j = 0; j < 4; ++j) {
                const int col = cw + 16 * j + fr;
                const float h = acc[j][reg];
                T2[col * D + SWZ(col, row)] = f2b(h);
                tk += h * b2f(Bk[col * D + SWZ(col, row)]); // Wk[row][col]
            }
        }
        for (int off = 32; off > 0; off >>= 1) tk += __shfl_down(tk, off);
        if (lane == 0) trsh[w] = tk;
    }
    __syncthreads();
    // H1 = G @ Wq -> trace_q
    {
        f32x4 acc[4] = {};
        gemm16x64(Ga, Bq, acc, rw, cw, fr, kg);
        float tq = 0.f;
#pragma unroll
        for (int reg = 0; reg < 4; ++reg) {
            const int row = rw + kg * 4 + reg;
#pragma unroll
            for (int j = 0; j < 4; ++j) {
                const int col = cw + 16 * j + fr;
                tq += acc[j][reg] * b2f(Bq[col * D + SWZ(col, row)]);
            }
        }
        for (int off = 32; off > 0; off >>= 1) tq += __shfl_down(tq, off);
        if (lane == 0) trsh[16 + w] = tq;
    }
    __syncthreads();
    if (t == 0) {
        float sk = 0.f, sq = 0.f;
#pragma unroll
        for (int i = 0; i < 16; ++i) { sk += trsh[i]; sq += trsh[16 + i]; }
        invS = 1.0f / (sqrtf(sq) * sqrtf(sk) * 128.0f);
    }
    if (t < D) {
        float s = 0.f;
#pragma unroll 8
        for (int j = 0; j < D; ++j) s += csx[j] * Wk[j * D + t];
        ksum[t] = s;
    }
    // restage: Ga <- Wq (A-layout, vectorized), Bq <- Av (B-layout, from stripV bf16)
#pragma unroll
    for (int p = 0; p < 4; ++p) {
        const int e4 = t + 1024 * p;
        const int e = e4 * 4;
        const int i = e >> 7, m = e & 127;
        const float4 q = *(const float4*)(Wq + e);
        u16 qb[4] = {f2b(q.x), f2b(q.y), f2b(q.z), f2b(q.w)};
        *(uint2*)(Ga + i * D + SWZ(i, m)) = *(const uint2*)qb;
    }
#pragma unroll
    for (int p = 0; p < 2; ++p) {
        const int e8 = (t + 1024 * p) * 8;
        const int n = e8 >> 7, i0 = e8 & 127;
        *(uint4*)(Bq + n * D + SWZ(n, i0)) = *(const uint4*)(stripV + n * D + i0);
    }
    __syncthreads();
    // C = T2(H2^T) @ Bq(Av) -> Bk <- (C*inv) B-layout; xkq
    {
        f32x4 acc[4] = {};
        gemm16x64(T2, Bq, acc, rw, cw, fr, kg);
        const float inv = invS;
#pragma unroll
        for (int reg = 0; reg < 4; ++reg) {
            const int m = rw + kg * 4 + reg;
#pragma unroll
            for (int j = 0; j < 4; ++j) {
                const int n = cw + 16 * j + fr;
                Bk[n * D + SWZ(n, m)] = f2b(acc[j][reg] * inv);
            }
        }
    }
    if (t < D) {
        float s = 0.f;
        const float inv = invS;
#pragma unroll 8
        for (int o = 0; o < D; ++o) s += Wq[t * D + o] * ksum[o];
        xkq[t] = s * inv;
    }
    __syncthreads();
    // C4 = Ga(Wq) @ Bk(C*inv); C5b[n][i] = Av[i][n] + C4[i][n]
    {
        f32x4 acc[4] = {};
        gemm16x64(Ga, Bk, acc, rw, cw, fr, kg);
#pragma unroll
        for (int reg = 0; reg < 4; ++reg) {
            const int r = rw + kg * 4 + reg; // C4 row i-index
#pragma unroll
            for (int j = 0; j < 4; ++j) {
                const int n = cw + 16 * j + fr;
                C5b[n * D + r] = f2b(b2f(stripV[n * D + r]) + acc[j][reg]);
            }
        }
    }
}

// ---------------- K-U: u = x @ stripU (single-matrix MFMA GEMM) ----------------
__global__ __launch_bounds__(256) void k_ugemm(const float* __restrict__ x,
                                               const u16* __restrict__ stripU,
                                               u16* __restrict__ ub, int M)
{
    __shared__ u16 As[64 * D];
    __shared__ u16 Bs[64 * D];
    const int t = threadIdx.x;
    const int row0 = blockIdx.x * 64;

#pragma unroll
    for (int p = 0; p < 4; ++p) {
        const int flat = t + 256 * p;
        const int r = flat >> 4, kg = flat & 15;
        int gr = row0 + r; if (gr > M - 1) gr = M - 1;
        const float4 f0 = *(const float4*)(x + (size_t)gr * D + kg * 8);
        const float4 f1 = *(const float4*)(x + (size_t)gr * D + kg * 8 + 4);
        u16 rr[8] = {f2b(f0.x), f2b(f0.y), f2b(f0.z), f2b(f0.w),
                     f2b(f1.x), f2b(f1.y), f2b(f1.z), f2b(f1.w)};
        *(uint4*)(As + r * D + SWZ(r, kg * 8)) = *(const uint4*)rr;
    }
#pragma unroll
    for (int p = 0; p < 4; ++p) {
        const int flat = t + 256 * p;
        const int r = flat >> 4, kg = flat & 15;
        const uint4 v = *(const uint4*)(stripU + (size_t)r * D + kg * 8);
        *(uint4*)(Bs + r * D + SWZ(r, kg * 8)) = v;
    }
    __syncthreads();

    const int lane = t & 63, w = t >> 6;
    const int wr = (w >> 1) * 32, wc = (w & 1) * 32;
    const int fr = lane & 15, kg2 = lane >> 4;

#pragma unroll
    for (int h = 0; h < 2; ++h) {
        f32x4 acc[2][2] = {};
#pragma unroll
        for (int ks = 0; ks < 4; ++ks) {
            const int kb = ks * 32 + kg2 * 8;
            bf16x8 a[2], b[2];
#pragma unroll
            for (int i = 0; i < 2; ++i) {
                const int r = wr + 16 * i + fr;
                a[i] = *(const bf16x8*)(As + r * D + SWZ(r, kb));
            }
#pragma unroll
            for (int j = 0; j < 2; ++j) {
                const int r = wc + 16 * j + fr;
                b[j] = *(const bf16x8*)(Bs + r * D + SWZ(r, kb));
            }
#pragma unroll
            for (int i = 0; i < 2; ++i)
#pragma unroll
                for (int j = 0; j < 2; ++j)
                    acc[i][j] = __builtin_amdgcn_mfma_f32_16x16x32_bf16(a[i], b[j], acc[i][j], 0, 0, 0);
        }
        __syncthreads();
        if (h == 0) {
#pragma unroll
            for (int p = 0; p < 4; ++p) {
                const int flat = t + 256 * p;
                const int r = flat >> 4, kg = flat & 15;
                const uint4 v = *(const uint4*)(stripU + (size_t)(64 + r) * D + kg * 8);
                *(uint4*)(Bs + r * D + SWZ(r, kg * 8)) = v;
            }
        }
        const int col0 = h * 64;
#pragma unroll
        for (int i = 0; i < 2; ++i) {
#pragma unroll
            for (int reg = 0; reg < 4; ++reg) {
                const int r = row0 + wr + 16 * i + kg2 * 4 + reg;
                if (r < M) {
#pragma unroll
                    for (int j = 0; j < 2; ++j) {
                        const int col = col0 + wc + 16 * j + fr;
                        ub[(size_t)r * D + col] = f2b(acc[i][j][reg]);
                    }
                }
            }
        }
        if (h == 0) __syncthreads();
    }
}

// ---------------- K-FINAL: out = rc*(x@C5) + 0.24*(x@Wl^T) + bias + sc*u ----------------
__global__ __launch_bounds__(256) void k_final(const float* __restrict__ x,
                                               const u16* __restrict__ C5b,
                                               const u16* __restrict__ stripL,
                                               const u16* __restrict__ ub,
                                               const int* __restrict__ cnt,
                                               const float* __restrict__ xkq,
                                               const float* __restrict__ biasout,
                                               float* __restrict__ out, int M)
{
    __shared__ u16 As[64 * D];
    __shared__ u16 Bs[64 * D];
    __shared__ float scaleS[64];
    const int t = threadIdx.x;
    const int row0 = blockIdx.x * 64;
    const int half = blockIdx.y;

#pragma unroll
    for (int p = 0; p < 4; ++p) {
        const int flat = t + 256 * p;
        const int r = flat >> 4, kg = flat & 15;
        int gr = row0 + r; if (gr > M - 1) gr = M - 1;
        const float4 f0 = *(const float4*)(x + (size_t)gr * D + kg * 8);
        const float4 f1 = *(const float4*)(x + (size_t)gr * D + kg * 8 + 4);
        u16 rr[8] = {f2b(f0.x), f2b(f0.y), f2b(f0.z), f2b(f0.w),
                     f2b(f1.x), f2b(f1.y), f2b(f1.z), f2b(f1.w)};
        *(uint4*)(As + r * D + SWZ(r, kg * 8)) = *(const uint4*)rr;
    }
#pragma unroll
    for (int p = 0; p < 4; ++p) {
        const int flat = t + 256 * p;
        const int r = flat >> 4, kg = flat & 15;
        const uint4 v = *(const uint4*)(C5b + (size_t)(half * 64 + r) * D + kg * 8);
        *(uint4*)(Bs + r * D + SWZ(r, kg * 8)) = v;
    }
    __syncthreads();

    // rc: qk_r = x_r . xkq
    {
        const int rr = t >> 2, qq = t & 3;
        float s = 0.f;
#pragma unroll
        for (int i = 0; i < 4; ++i) {
            const int kk = qq * 32 + i * 8;
            const bf16x8 a = *(const bf16x8*)(As + rr * D + SWZ(rr, kk));
            const u16* ap = (const u16*)&a;
#pragma unroll
            for (int jj = 0; jj < 8; ++jj) s += b2f(ap[jj]) * xkq[kk + jj];
        }
        s += __shfl_xor(s, 1);
        s += __shfl_xor(s, 2);
        if (qq == 0) scaleS[rr] = 0.16f / (1.0f + s);
    }

    const int lane = t & 63, w = t >> 6;
    const int wr = (w >> 1) * 32, wc = (w & 1) * 32;
    const int fr = lane & 15, kg2 = lane >> 4;

    f32x4 acc1[2][2] = {};
#pragma unroll
    for (int ks = 0; ks < 4; ++ks) {
        const int kb = ks * 32 + kg2 * 8;
        bf16x8 a[2], b[2];
#pragma unroll
        for (int i = 0; i < 2; ++i) {
            const int r = wr + 16 * i + fr;
            a[i] = *(const bf16x8*)(As + r * D + SWZ(r, kb));
        }
#pragma unroll
        for (int j = 0; j < 2; ++j) {
            const int r = wc + 16 * j + fr;
            b[j] = *(const bf16x8*)(Bs + r * D + SWZ(r, kb));
        }
#pragma unroll
        for (int i = 0; i < 2; ++i)
#pragma unroll
            for (int j = 0; j < 2; ++j)
                acc1[i][j] = __builtin_amdgcn_mfma_f32_16x16x32_bf16(a[i], b[j], acc1[i][j], 0, 0, 0);
    }
    __syncthreads();
    // restage Bs <- stripL rows (half*64 ..)
#pragma unroll
    for (int p = 0; p < 4; ++p) {
        const int flat = t + 256 * p;
        const int r = flat >> 4, kg = flat & 15;
        const uint4 v = *(const uint4*)(stripL + (size_t)(half * 64 + r) * D + kg * 8);
        *(uint4*)(Bs + r * D + SWZ(r, kg * 8)) = v;
    }
    __syncthreads();

    f32x4 acc2[2][2] = {};
#pragma unroll
    for (int ks = 0; ks < 4; ++ks) {
        const int kb = ks * 32 + kg2 * 8;
        bf16x8 a[2], b[2];
#pragma unroll
        for (int i = 0; i < 2; ++i) {
            const int r = wr + 16 * i + fr;
            a[i] = *(const bf16x8*)(As + r * D + SWZ(r, kb));
        }
#pragma unroll
        for (int j = 0; j < 2; ++j) {
            const int r = wc + 16 * j + fr;
            b[j] = *(const bf16x8*)(Bs + r * D + SWZ(r, kb));
        }
#pragma unroll
        for (int i = 0; i < 2; ++i)
#pragma unroll
            for (int j = 0; j < 2; ++j)
                acc2[i][j] = __builtin_amdgcn_mfma_f32_16x16x32_bf16(a[i], b[j], acc2[i][j], 0, 0, 0);
    }

#pragma unroll
    for (int i = 0; i < 2; ++i) {
#pragma unroll
        for (int reg = 0; reg < 4; ++reg) {
            const int rloc = wr + 16 * i + kg2 * 4 + reg;
            const int r = row0 + rloc;
            if (r < M) {
                const float rc = scaleS[rloc];
                const float sc = 1.0f / (float)(cnt[r] + 1);
#pragma unroll
                for (int j = 0; j < 2; ++j) {
                    const int c = half * 64 + wc + 16 * j + fr;
                    const size_t idx = (size_t)r * D + c;
                    out[idx] = rc * acc1[i][j][reg] + 0.24f * acc2[i][j][reg]
                             + biasout[c] + sc * b2f(ub[idx]);
                }
            }
        }
    }
}

// ---------------- K5: wave-cooperative CSR gather, 16 edges in flight ----------------
__global__ __launch_bounds__(256) void k_gather(const int* __restrict__ offs,
                                                const int* __restrict__ cnt,
                                                const uint32_t* __restrict__ cpk,
                                                const u16* __restrict__ ub,
                                                float* __restrict__ out, int M)
{
    const int t = threadIdx.x;
    const int w = t >> 6, lane = t & 63;
    const int d = blockIdx.x * 4 + w;
    if (d >= M) return;
    const int g = lane >> 4, sub = lane & 15;
    const int beg = offs[d];
    const int n = cnt[d];
    if (n == 0) return;
    const int end = beg + n;
    float acc[8] = {};
    for (int j0 = beg; j0 < end; j0 += 16) {
        int ss[4]; float ww[4];
#pragma unroll
        for (int q = 0; q < 4; ++q) {
            const int j = j0 + 4 * q + g;
            int s = 0; float wv = 0.f;
            if (j < end) {
                const uint32_t p = cpk[j];
                s = (int)(p & 0xFFFFu);
                wv = __half2float(__ushort_as_half((u16)(p >> 16)));
            }
            ss[q] = s; ww[q] = wv;
        }
        uint4 rr[4];
#pragma unroll
        for (int q = 0; q < 4; ++q)
            rr[q] = *(const uint4*)(ub + (size_t)ss[q] * D + sub * 8);
#pragma unroll
        for (int q = 0; q < 4; ++q) {
            const u16* p = (const u16*)&rr[q];
            const float wv = ww[q];
#pragma unroll
            for (int i = 0; i < 8; ++i) acc[i] += wv * b2f(p[i]);
        }
    }
#pragma unroll
    for (int i = 0; i < 8; ++i) {
        acc[i] += __shfl_xor(acc[i], 16);
        acc[i] += __shfl_xor(acc[i], 32);
    }
    if (g == 0) {
        float* o = out + (size_t)d * D + sub * 8;
        float4 o0 = *(float4*)o, o1 = *(float4*)(o + 4);
        o0.x += acc[0]; o0.y += acc[1]; o0.z += acc[2]; o0.w += acc[3];
        o1.x += acc[4]; o1.y += acc[5]; o1.z += acc[6]; o1.w += acc[7];
        *(float4*)o = o0; *(float4*)(o + 4) = o1;
    }
}

extern "C" void kernel_launch(void* const* d_in, const int* in_sizes, int n_in,
                              void* d_out, int out_size, void* d_ws, size_t ws_size,
                              hipStream_t stream)
{
    const float* x  = (const float*)d_in[0];
    const int*   ei = (const int*)d_in[1];
    const float* Wq = (const float*)d_in[2];
    const float* Wk = (const float*)d_in[3];
    const float* Wv = (const float*)d_in[4];
    const float* Wg = (const float*)d_in[5];
    const float* bg = (const float*)d_in[6];
    const float* Wl = (const float*)d_in[7];
    const float* bl = (const float*)d_in[8];

    const int M = in_sizes[0] / D;
    const int E = in_sizes[1] / 2;
    const size_t NQ = (size_t)M * D;
    const int P = 512;
    const int NBG = (M + 63) / 64;
    const int NB = (M + 1023) / 1024;

    char* base = (char*)d_ws;
    auto alloc = [&](size_t bytes) -> char* {
        char* p = base; base += (bytes + 63) & ~(size_t)63; return p;
    };
    u16*   part    = (u16*)alloc((size_t)P * D * D * 2);
    float* Graw    = (float*)alloc(D * D * 4);
    float* pcs     = (float*)alloc((size_t)P * D * 4);
    float* csx     = (float*)alloc(D * 4);
    float* dinv    = (float*)alloc((size_t)M * 4);
    float* xkq     = (float*)alloc(D * 4);
    float* biasout = (float*)alloc(D * 4);
    int*   cnt     = (int*)alloc((size_t)M * 4);
    int*   offs    = (int*)alloc((size_t)M * 4);
    int*   bsum    = (int*)alloc(64 * 4);
    int*   epos    = (int*)alloc((size_t)E * 4);
    uint32_t* cpk  = (uint32_t*)alloc((size_t)E * 4);
    u16*   Bcatb   = (u16*)alloc((size_t)384 * D * 2);
    u16*   C5b     = (u16*)alloc(D * D * 2);
    u16*   ub      = (u16*)alloc(NQ * 2);

    const u16* stripV = Bcatb;
    const u16* stripL = Bcatb + D * D;
    const u16* stripU = Bcatb + 2 * D * D;

    float* out = (float*)d_out;

    // weights + CSR build
    k_prep<<<dim3(385), dim3(128), 0, stream>>>(Wv, Wg, bg, Wl, bl, Bcatb, biasout);
    k_init<<<(M + 255) / 256, 256, 0, stream>>>(cnt, M);
    k_hist<<<(E + 255) / 256, 256, 0, stream>>>(ei + E, cnt, epos, E);
    k_scan1<<<NB, 1024, 0, stream>>>(cnt, offs, bsum, dinv, M);
    k_scanB<<<1, 64, 0, stream>>>(bsum, NB);
    k_scan2<<<(M + 255) / 256, 256, 0, stream>>>(bsum, offs, M);
    k_fill<<<(E + 255) / 256, 256, 0, stream>>>(ei, ei + E, epos, dinv, offs, cpk, E);

    // dense chain (Gram restructure)
    k_gram<<<P, 256, 0, stream>>>(x, part, pcs, M);
    k_redC<<<72, 256, 0, stream>>>(part, Graw, pcs, csx, P);
    k_small<<<1, 1024, 0, stream>>>(Graw, csx, Wq, Wk, stripV, xkq, C5b);
    k_ugemm<<<NBG, 256, 0, stream>>>(x, stripU, ub, M);
    k_final<<<dim3(NBG, 2), 256, 0, stream>>>(x, C5b, stripL, ub, cnt, xkq, biasout, out, M);
    k_gather<<<(M + 3) / 4, 256, 0, stream>>>(offs, cnt, cpk, ub, out, M);
}

// Round 15
// 176.289 us; speedup vs baseline: 1.0711x; 1.0553x over previous
//
#include <hip/hip_runtime.h>
#include <hip/hip_fp16.h>
#include <cstdint>
#include <cstddef>

#define D 128
#define XTS 72  // padded row stride (u16) for transposed tiles: 144B = 9*16B, bank-rotating
typedef unsigned short u16;
typedef short bf16x8 __attribute__((ext_vector_type(8)));
typedef float f32x4 __attribute__((ext_vector_type(4)));

// bf16 pack/unpack (RTNE)
__device__ __forceinline__ u16 f2b(float f) {
    uint32_t u = __float_as_uint(f);
    return (u16)((u + 0x7FFFu + ((u >> 16) & 1u)) >> 16);
}
__device__ __forceinline__ float b2f(u16 b) {
    return __uint_as_float(((uint32_t)b) << 16);
}

// XOR swizzle on bf16 k-index within a [rows][128] LDS tile (16B groups)
#define SWZ(r, k) ((k) ^ (((r) & 7) << 3))

// ---------------- K0: fold weights -> bf16 strips; zero cnt + bsum ----------------
__global__ void k_prep(const float* __restrict__ Wv, const float* __restrict__ Wg,
                       const float* __restrict__ bg, const float* __restrict__ Wl,
                       const float* __restrict__ bl,
                       u16* __restrict__ Bcatb, float* __restrict__ biasout,
                       int* __restrict__ cnt, int* __restrict__ bsum, int M)
{
    const int b = blockIdx.x;
    const int t = threadIdx.x; // 128
    if (b < 384) {
        const int strip = b >> 7, n = b & 127;
        float val;
        if (strip == 0) {
            float s = 0.f;
#pragma unroll 8
            for (int m = 0; m < D; ++m) s += Wv[t * D + m] * Wl[n * D + m];
            val = s;
        } else if (strip == 1) {
            val = Wl[n * D + t];
        } else {
            float s = 0.f;
#pragma unroll 8
            for (int m = 0; m < D; ++m) s += Wl[n * D + m] * Wg[m * D + t];
            val = 0.6f * s;
        }
        Bcatb[(size_t)b * D + t] = f2b(val);
    } else if (b == 384) {
        float s = 0.f;
#pragma unroll 8
        for (int m = 0; m < D; ++m) s += bg[m] * Wl[t * D + m];
        biasout[t] = bl[t] + 0.6f * s;
        if (t < 64) bsum[t] = 0;
    } else {
        const int i = (b - 385) * 128 + t;
        if (i < M) cnt[i] = 0;
    }
}

// histogram + record within-segment position
__global__ void k_hist(const int* __restrict__ dst, int* __restrict__ cnt,
                       int* __restrict__ epos, int E)
{
    const int e = blockIdx.x * 256 + threadIdx.x;
    if (e < E) epos[e] = atomicAdd(&cnt[dst[e]], 1);
}

// ---------------- per-1024 scan (+ dinv fused); offs stays segment-local ----------------
__global__ __launch_bounds__(1024) void k_scan1(const int* __restrict__ cnt,
                                                int* __restrict__ offs,
                                                int* __restrict__ bsum,
                                                float* __restrict__ dinv, int M)
{
    __shared__ int wsum[16];
    const int t = threadIdx.x, lane = t & 63, w = t >> 6;
    const int i = blockIdx.x * 1024 + t;
    const int v = (i < M) ? cnt[i] : 0;
    if (i < M) dinv[i] = rsqrtf((float)(v + 1)); // +1 self loop
    int s = v;
    for (int off = 1; off < 64; off <<= 1) {
        int n = __shfl_up(s, off);
        if (lane >= off) s += n;
    }
    if (lane == 63) wsum[w] = s;
    __syncthreads();
    if (w == 0) {
        int ss = (lane < 16) ? wsum[lane] : 0;
        for (int off = 1; off < 16; off <<= 1) {
            int n = __shfl_up(ss, off);
            if (lane >= off) ss += n;
        }
        if (lane < 16) wsum[lane] = ss;
    }
    __syncthreads();
    const int woff = (w == 0) ? 0 : wsum[w - 1];
    if (i < M) offs[i] = woff + s - v;
    if (t == 1023) bsum[blockIdx.x] = wsum[15];
}

// fill CSR, atomic-free: pos = segprefix + offs[d] + epos[e]; payload = src | fp16(w)<<16
__global__ void k_fill(const int* __restrict__ src, const int* __restrict__ dst,
                       const int* __restrict__ epos,
                       const float* __restrict__ dinv,
                       const int* __restrict__ offs,
                       const int* __restrict__ bsum,
                       uint32_t* __restrict__ cpk, int E)
{
    __shared__ int sbcar[64];
    const int t = threadIdx.x;
    if (t < 64) {
        const int v = bsum[t];
        int s = v;
        for (int off = 1; off < 64; off <<= 1) {
            int n = __shfl_up(s, off);
            if (t >= off) s += n;
        }
        sbcar[t] = s - v; // exclusive segment prefix
    }
    __syncthreads();
    const int e = blockIdx.x * 256 + t;
    if (e < E) {
        const int s = src[e], d = dst[e];
        const int pos = sbcar[d >> 10] + offs[d] + epos[e];
        const float w = dinv[s] * dinv[d];
        const u16 hb = __half_as_ushort(__float2half(w));
        cpk[pos] = (uint32_t)(u16)s | ((uint32_t)hb << 16);
    }
}

// ---------------- K-GRAM: split-K partials of G = X^T X + colsum(X) ----------------
__global__ __launch_bounds__(256) void k_gram(const float* __restrict__ x,
                                              u16* __restrict__ part,
                                              float* __restrict__ pcs, int M)
{
    __shared__ u16 xT[D * XTS]; // xT[c][r], row stride 72
    const int t = threadIdx.x;
    const int P = (int)gridDim.x;
    const int chunk = (M + P - 1) / P;
    const int rbeg = blockIdx.x * chunk;
    const int rend = min(rbeg + chunk, M);
    const int lane = t & 63, w = t >> 6;
    const int fr = lane & 15, kg = lane >> 4;

    f32x4 acc[2][8] = {};
    float csacc = 0.f;

    for (int r0 = rbeg; r0 < rend; r0 += 64) {
#pragma unroll
        for (int p = 0; p < 8; ++p) {
            const int flat = t + 256 * p;   // 2048 float4 slots
            const int rr = flat & 63;       // row = lane within wave
            const int c4 = flat >> 6;       // col-group, fixed per wave
            const int gr = r0 + rr;
            float4 v = make_float4(0.f, 0.f, 0.f, 0.f);
            if (gr < rend) v = *(const float4*)(x + (size_t)gr * D + c4 * 4);
            u16* dst = xT + (c4 * 4) * XTS + rr;
            dst[0]       = f2b(v.x);
            dst[XTS]     = f2b(v.y);
            dst[2 * XTS] = f2b(v.z);
            dst[3 * XTS] = f2b(v.w);
        }
        __syncthreads();
#pragma unroll
        for (int ks = 0; ks < 2; ++ks) {
            const int rb = ks * 32 + kg * 8;
            bf16x8 a[2], b[8];
#pragma unroll
            for (int i = 0; i < 2; ++i) {
                const int m = w * 32 + 16 * i + fr;
                a[i] = *(const bf16x8*)(xT + m * XTS + rb);
            }
#pragma unroll
            for (int j = 0; j < 8; ++j) {
                const int n = 16 * j + fr;
                b[j] = *(const bf16x8*)(xT + n * XTS + rb);
            }
#pragma unroll
            for (int i = 0; i < 2; ++i)
#pragma unroll
                for (int j = 0; j < 8; ++j)
                    acc[i][j] = __builtin_amdgcn_mfma_f32_16x16x32_bf16(a[i], b[j], acc[i][j], 0, 0, 0);
        }
        // colsum of this tile (register-accumulated; no atomics)
        if (t < D) {
            const u16* col = xT + t * XTS;
#pragma unroll 16
            for (int r = 0; r < 64; ++r) csacc += b2f(col[r]);
        }
        __syncthreads();
    }
    u16* pp = part + (size_t)blockIdx.x * (D * D);
#pragma unroll
    for (int i = 0; i < 2; ++i)
#pragma unroll
        for (int reg = 0; reg < 4; ++reg) {
            const int m = w * 32 + 16 * i + kg * 4 + reg;
#pragma unroll
            for (int j = 0; j < 8; ++j)
                pp[(size_t)m * D + 16 * j + fr] = f2b(acc[i][j][reg]);
        }
    if (t < D) pcs[(size_t)blockIdx.x * D + t] = csacc;
}

// split-K reduce: blocks 0..63 reduce part (bf16) -> Graw; blocks 64..71 reduce pcs -> csx
__global__ void k_redC(const u16* __restrict__ part, float* __restrict__ Craw,
                       const float* __restrict__ pcs, float* __restrict__ csx, int P)
{
    if (blockIdx.x < 64) {
        const int e = blockIdx.x * 256 + threadIdx.x; // 16384
        float s0 = 0.f, s1 = 0.f, s2 = 0.f, s3 = 0.f,
              s4 = 0.f, s5 = 0.f, s6 = 0.f, s7 = 0.f;
        int p = 0;
        for (; p + 8 <= P; p += 8) {
            s0 += b2f(part[(size_t)(p + 0) * (D * D) + e]);
            s1 += b2f(part[(size_t)(p + 1) * (D * D) + e]);
            s2 += b2f(part[(size_t)(p + 2) * (D * D) + e]);
            s3 += b2f(part[(size_t)(p + 3) * (D * D) + e]);
            s4 += b2f(part[(size_t)(p + 4) * (D * D) + e]);
            s5 += b2f(part[(size_t)(p + 5) * (D * D) + e]);
            s6 += b2f(part[(size_t)(p + 6) * (D * D) + e]);
            s7 += b2f(part[(size_t)(p + 7) * (D * D) + e]);
        }
        for (; p < P; ++p) s0 += b2f(part[(size_t)p * (D * D) + e]);
        Craw[e] = ((s0 + s1) + (s2 + s3)) + ((s4 + s5) + (s6 + s7));
    } else {
        __shared__ float red[16][16];
        const int pb = blockIdx.x - 64;         // 0..7
        const int cl = threadIdx.x & 15;        // col within group
        const int sl = threadIdx.x >> 4;        // slice 0..15
        const int col = pb * 16 + cl;
        float s = 0.f;
#pragma unroll 8
        for (int p = sl; p < P; p += 16) s += pcs[(size_t)p * D + col];
        red[sl][cl] = s;
        __syncthreads();
        if (sl == 0) {
            float tot = 0.f;
#pragma unroll
            for (int i = 0; i < 16; ++i) tot += red[i][cl];
            csx[col] = tot;
        }
    }
}

// per-wave 16x64 patch of a 128x128 GEMM (16 waves cover all)
__device__ __forceinline__ void gemm16x64(const u16* __restrict__ A,
                                          const u16* __restrict__ B,
                                          f32x4 acc[4], int rw, int cw,
                                          int fr, int kg)
{
#pragma unroll
    for (int ks = 0; ks < 4; ++ks) {
        const int kb = ks * 32 + kg * 8;
        const int r = rw + fr;
        const bf16x8 a = *(const bf16x8*)(A + r * D + SWZ(r, kb));
#pragma unroll
        for (int j = 0; j < 4; ++j) {
            const int n = cw + 16 * j + fr;
            const bf16x8 b = *(const bf16x8*)(B + n * D + SWZ(n, kb));
            acc[j] = __builtin_amdgcn_mfma_f32_16x16x32_bf16(a, b, acc[j], 0, 0, 0);
        }
    }
}

// ---------------- K-SMALL: all 128x128 algebra, 1024 threads (16 waves) ----------------
__global__ __launch_bounds__(1024) void k_small(const float* __restrict__ Graw,
                                                const float* __restrict__ csx_g,
                                                const float* __restrict__ Wq,
                                                const float* __restrict__ Wk,
                                                const u16* __restrict__ stripV,
                                                float* __restrict__ xkq,
                                                u16* __restrict__ C5b)
{
    __shared__ u16 Ga[D * D]; // G A-layout -> later Wq A-layout
    __shared__ u16 Bq[D * D]; // Wq B-layout -> later Av B-layout
    __shared__ u16 Bk[D * D]; // Wk B-layout -> later (C*inv) B-layout
    __shared__ u16 T2[D * D]; // H2^T A-layout
    __shared__ float csx[D];
    __shared__ float ksum[D];
    __shared__ float trsh[32];
    __shared__ float invS;
    const int t = threadIdx.x;
    const int lane = t & 63, w = t >> 6;       // 16 waves
    const int fr = lane & 15, kg = lane >> 4;
    const int rw = (w & 7) * 16, cw = (w >> 3) * 64;

    if (t < D) csx[t] = csx_g[t];
    // stage: Ga = G (A-layout, vectorized), Bq/Bk = Wq/Wk (B-layout = transpose)
#pragma unroll
    for (int p = 0; p < 4; ++p) {
        const int e4 = t + 1024 * p;  // 4096 float4 groups
        const int e = e4 * 4;
        const int i = e >> 7, m = e & 127;
        const float4 g = *(const float4*)(Graw + e);
        u16 gb[4] = {f2b(g.x), f2b(g.y), f2b(g.z), f2b(g.w)};
        *(uint2*)(Ga + i * D + SWZ(i, m)) = *(const uint2*)gb;
        const float4 q = *(const float4*)(Wq + e);
        const float4 k = *(const float4*)(Wk + e);
        Bq[(m + 0) * D + SWZ(m + 0, i)] = f2b(q.x);
        Bq[(m + 1) * D + SWZ(m + 1, i)] = f2b(q.y);
        Bq[(m + 2) * D + SWZ(m + 2, i)] = f2b(q.z);
        Bq[(m + 3) * D + SWZ(m + 3, i)] = f2b(q.w);
        Bk[(m + 0) * D + SWZ(m + 0, i)] = f2b(k.x);
        Bk[(m + 1) * D + SWZ(m + 1, i)] = f2b(k.y);
        Bk[(m + 2) * D + SWZ(m + 2, i)] = f2b(k.z);
        Bk[(m + 3) * D + SWZ(m + 3, i)] = f2b(k.w);
    }
    __syncthreads();

    // H2 = G @ Wk -> T2 = H2^T (A-layout); trace_k
    {
        f32x4 acc[4] = {};
        gemm16x64(Ga, Bk, acc, rw, cw, fr, kg);
        float tk = 0.f;
#pragma unroll
        for (int reg = 0; reg < 4; ++reg) {
            const int row = rw + kg * 4 + reg;
#pragma unroll
            for (int j = 0; j < 4; ++j) {
                const int col = cw + 16 * j + fr;
                const float h = acc[j][reg];
                T2[col * D + SWZ(col, row)] = f2b(h);
                tk += h * b2f(Bk[col * D + SWZ(col, row)]); // Wk[row][col]
            }
        }
        for (int off = 32; off > 0; off >>= 1) tk += __shfl_down(tk, off);
        if (lane == 0) trsh[w] = tk;
    }
    __syncthreads();
    // H1 = G @ Wq -> trace_q
    {
        f32x4 acc[4] = {};
        gemm16x64(Ga, Bq, acc, rw, cw, fr, kg);
        float tq = 0.f;
#pragma unroll
        for (int reg = 0; reg < 4; ++reg) {
            const int row = rw + kg * 4 + reg;
#pragma unroll
            for (int j = 0; j < 4; ++j) {
                const int col = cw + 16 * j + fr;
                tq += acc[j][reg] * b2f(Bq[col * D + SWZ(col, row)]);
            }
        }
        for (int off = 32; off > 0; off >>= 1) tq += __shfl_down(tq, off);
        if (lane == 0) trsh[16 + w] = tq;
    }
    __syncthreads();
    if (t == 0) {
        float sk = 0.f, sq = 0.f;
#pragma unroll
        for (int i = 0; i < 16; ++i) { sk += trsh[i]; sq += trsh[16 + i]; }
        invS = 1.0f / (sqrtf(sq) * sqrtf(sk) * 128.0f);
    }
    if (t < D) {
        float s = 0.f;
#pragma unroll 8
        for (int j = 0; j < D; ++j) s += csx[j] * Wk[j * D + t];
        ksum[t] = s;
    }
    // restage: Ga <- Wq (A-layout, vectorized), Bq <- Av (B-layout, from stripV bf16)
#pragma unroll
    for (int p = 0; p < 4; ++p) {
        const int e4 = t + 1024 * p;
        const int e = e4 * 4;
        const int i = e >> 7, m = e & 127;
        const float4 q = *(const float4*)(Wq + e);
        u16 qb[4] = {f2b(q.x), f2b(q.y), f2b(q.z), f2b(q.w)};
        *(uint2*)(Ga + i * D + SWZ(i, m)) = *(const uint2*)qb;
    }
#pragma unroll
    for (int p = 0; p < 2; ++p) {
        const int e8 = (t + 1024 * p) * 8;
        const int n = e8 >> 7, i0 = e8 & 127;
        *(uint4*)(Bq + n * D + SWZ(n, i0)) = *(const uint4*)(stripV + n * D + i0);
    }
    __syncthreads();
    // C = T2(H2^T) @ Bq(Av) -> Bk <- (C*inv) B-layout; xkq
    {
        f32x4 acc[4] = {};
        gemm16x64(T2, Bq, acc, rw, cw, fr, kg);
        const float inv = invS;
#pragma unroll
        for (int reg = 0; reg < 4; ++reg) {
            const int m = rw + kg * 4 + reg;
#pragma unroll
            for (int j = 0; j < 4; ++j) {
                const int n = cw + 16 * j + fr;
                Bk[n * D + SWZ(n, m)] = f2b(acc[j][reg] * inv);
            }
        }
    }
    if (t < D) {
        float s = 0.f;
        const float inv = invS;
#pragma unroll 8
        for (int o = 0; o < D; ++o) s += Wq[t * D + o] * ksum[o];
        xkq[t] = s * inv;
    }
    __syncthreads();
    // C4 = Ga(Wq) @ Bk(C*inv); C5b[n][i] = Av[i][n] + C4[i][n]
    {
        f32x4 acc[4] = {};
        gemm16x64(Ga, Bk, acc, rw, cw, fr, kg);
#pragma unroll
        for (int reg = 0; reg < 4; ++reg) {
            const int r = rw + kg * 4 + reg; // C4 row i-index
#pragma unroll
            for (int j = 0; j < 4; ++j) {
                const int n = cw + 16 * j + fr;
                C5b[n * D + r] = f2b(b2f(stripV[n * D + r]) + acc[j][reg]);
            }
        }
    }
}

// ---------------- K-DENSE: u = x@U; out = rc*(x@C5) + 0.24*(x@Wl^T) + bias + sc*u ----------------
// grid (NBG, 2): blockIdx.y = 64-col half. Writes ub (bf16, for gather) and out.
__global__ __launch_bounds__(256) void k_dense(const float* __restrict__ x,
                                               const u16* __restrict__ stripU,
                                               const u16* __restrict__ C5b,
                                               const u16* __restrict__ stripL,
                                               const int* __restrict__ cnt,
                                               const float* __restrict__ xkq,
                                               const float* __restrict__ biasout,
                                               u16* __restrict__ ub,
                                               float* __restrict__ out, int M)
{
    __shared__ u16 As[64 * D];
    __shared__ u16 Bs[64 * D];
    __shared__ float scaleS[64];
    const int t = threadIdx.x;
    const int row0 = blockIdx.x * 64;
    const int half = blockIdx.y;

#pragma unroll
    for (int p = 0; p < 4; ++p) {
        const int flat = t + 256 * p;
        const int r = flat >> 4, kg = flat & 15;
        int gr = row0 + r; if (gr > M - 1) gr = M - 1;
        const float4 f0 = *(const float4*)(x + (size_t)gr * D + kg * 8);
        const float4 f1 = *(const float4*)(x + (size_t)gr * D + kg * 8 + 4);
        u16 rr[8] = {f2b(f0.x), f2b(f0.y), f2b(f0.z), f2b(f0.w),
                     f2b(f1.x), f2b(f1.y), f2b(f1.z), f2b(f1.w)};
        *(uint4*)(As + r * D + SWZ(r, kg * 8)) = *(const uint4*)rr;
    }
#pragma unroll
    for (int p = 0; p < 4; ++p) {
        const int flat = t + 256 * p;
        const int r = flat >> 4, kg = flat & 15;
        const uint4 v = *(const uint4*)(stripU + (size_t)(half * 64 + r) * D + kg * 8);
        *(uint4*)(Bs + r * D + SWZ(r, kg * 8)) = v;
    }
    __syncthreads();

    // rc: qk_r = x_r . xkq (redundant per half, cheap)
    {
        const int rr = t >> 2, qq = t & 3;
        float s = 0.f;
#pragma unroll
        for (int i = 0; i < 4; ++i) {
            const int kk = qq * 32 + i * 8;
            const bf16x8 a = *(const bf16x8*)(As + rr * D + SWZ(rr, kk));
            const u16* ap = (const u16*)&a;
#pragma unroll
            for (int jj = 0; jj < 8; ++jj) s += b2f(ap[jj]) * xkq[kk + jj];
        }
        s += __shfl_xor(s, 1);
        s += __shfl_xor(s, 2);
        if (qq == 0) scaleS[rr] = 0.16f / (1.0f + s);
    }

    const int lane = t & 63, w = t >> 6;
    const int wr = (w >> 1) * 32, wc = (w & 1) * 32;
    const int fr = lane & 15, kg2 = lane >> 4;

    // GEMM 1: u half
    f32x4 accU[2][2] = {};
#pragma unroll
    for (int ks = 0; ks < 4; ++ks) {
        const int kb = ks * 32 + kg2 * 8;
        bf16x8 a[2], b[2];
#pragma unroll
        for (int i = 0; i < 2; ++i) {
            const int r = wr + 16 * i + fr;
            a[i] = *(const bf16x8*)(As + r * D + SWZ(r, kb));
        }
#pragma unroll
        for (int j = 0; j < 2; ++j) {
            const int r = wc + 16 * j + fr;
            b[j] = *(const bf16x8*)(Bs + r * D + SWZ(r, kb));
        }
#pragma unroll
        for (int i = 0; i < 2; ++i)
#pragma unroll
            for (int j = 0; j < 2; ++j)
                accU[i][j] = __builtin_amdgcn_mfma_f32_16x16x32_bf16(a[i], b[j], accU[i][j], 0, 0, 0);
    }
    __syncthreads();
    // restage Bs <- C5b half
#pragma unroll
    for (int p = 0; p < 4; ++p) {
        const int flat = t + 256 * p;
        const int r = flat >> 4, kg = flat & 15;
        const uint4 v = *(const uint4*)(C5b + (size_t)(half * 64 + r) * D + kg * 8);
        *(uint4*)(Bs + r * D + SWZ(r, kg * 8)) = v;
    }
    __syncthreads();

    // GEMM 2: attention half
    f32x4 acc1[2][2] = {};
#pragma unroll
    for (int ks = 0; ks < 4; ++ks) {
        const int kb = ks * 32 + kg2 * 8;
        bf16x8 a[2], b[2];
#pragma unroll
        for (int i = 0; i < 2; ++i) {
            const int r = wr + 16 * i + fr;
            a[i] = *(const bf16x8*)(As + r * D + SWZ(r, kb));
        }
#pragma unroll
        for (int j = 0; j < 2; ++j) {
            const int r = wc + 16 * j + fr;
            b[j] = *(const bf16x8*)(Bs + r * D + SWZ(r, kb));
        }
#pragma unroll
        for (int i = 0; i < 2; ++i)
#pragma unroll
            for (int j = 0; j < 2; ++j)
                acc1[i][j] = __builtin_amdgcn_mfma_f32_16x16x32_bf16(a[i], b[j], acc1[i][j], 0, 0, 0);
    }
    __syncthreads();
    // restage Bs <- stripL half
#pragma unroll
    for (int p = 0; p < 4; ++p) {
        const int flat = t + 256 * p;
        const int r = flat >> 4, kg = flat & 15;
        const uint4 v = *(const uint4*)(stripL + (size_t)(half * 64 + r) * D + kg * 8);
        *(uint4*)(Bs + r * D + SWZ(r, kg * 8)) = v;
    }
    __syncthreads();

    // GEMM 3: xW half
    f32x4 acc2[2][2] = {};
#pragma unroll
    for (int ks = 0; ks < 4; ++ks) {
        const int kb = ks * 32 + kg2 * 8;
        bf16x8 a[2], b[2];
#pragma unroll
        for (int i = 0; i < 2; ++i) {
            const int r = wr + 16 * i + fr;
            a[i] = *(const bf16x8*)(As + r * D + SWZ(r, kb));
        }
#pragma unroll
        for (int j = 0; j < 2; ++j) {
            const int r = wc + 16 * j + fr;
            b[j] = *(const bf16x8*)(Bs + r * D + SWZ(r, kb));
        }
#pragma unroll
        for (int i = 0; i < 2; ++i)
#pragma unroll
            for (int j = 0; j < 2; ++j)
                acc2[i][j] = __builtin_amdgcn_mfma_f32_16x16x32_bf16(a[i], b[j], acc2[i][j], 0, 0, 0);
    }

    // epilogue: write ub (bf16) + out (u used in-register)
#pragma unroll
    for (int i = 0; i < 2; ++i) {
#pragma unroll
        for (int reg = 0; reg < 4; ++reg) {
            const int rloc = wr + 16 * i + kg2 * 4 + reg;
            const int r = row0 + rloc;
            if (r < M) {
                const float rc = scaleS[rloc];
                const float sc = 1.0f / (float)(cnt[r] + 1);
#pragma unroll
                for (int j = 0; j < 2; ++j) {
                    const int c = half * 64 + wc + 16 * j + fr;
                    const size_t idx = (size_t)r * D + c;
                    const float uv = accU[i][j][reg];
                    ub[idx] = f2b(uv);
                    out[idx] = rc * acc1[i][j][reg] + 0.24f * acc2[i][j][reg]
                             + biasout[c] + sc * uv;
                }
            }
        }
    }
}

// ---------------- K5: wave-cooperative CSR gather, 16 edges in flight ----------------
__global__ __launch_bounds__(256) void k_gather(const int* __restrict__ offs,
                                                const int* __restrict__ cnt,
                                                const int* __restrict__ bsum,
                                                const uint32_t* __restrict__ cpk,
                                                const u16* __restrict__ ub,
                                                float* __restrict__ out, int M)
{
    __shared__ int sbcar[64];
    const int t = threadIdx.x;
    if (t < 64) {
        const int v = bsum[t];
        int s = v;
        for (int off = 1; off < 64; off <<= 1) {
            int n = __shfl_up(s, off);
            if (t >= off) s += n;
        }
        sbcar[t] = s - v;
    }
    __syncthreads();
    const int w = t >> 6, lane = t & 63;
    const int d = blockIdx.x * 4 + w;
    if (d >= M) return;
    const int g = lane >> 4, sub = lane & 15;
    const int n = cnt[d];
    if (n == 0) return;
    const int beg = sbcar[d >> 10] + offs[d];
    const int end = beg + n;
    float acc[8] = {};
    for (int j0 = beg; j0 < end; j0 += 16) {
        int ss[4]; float ww[4];
#pragma unroll
        for (int q = 0; q < 4; ++q) {
            const int j = j0 + 4 * q + g;
            int s = 0; float wv = 0.f;
            if (j < end) {
                const uint32_t p = cpk[j];
                s = (int)(p & 0xFFFFu);
                wv = __half2float(__ushort_as_half((u16)(p >> 16)));
            }
            ss[q] = s; ww[q] = wv;
        }
        uint4 rr[4];
#pragma unroll
        for (int q = 0; q < 4; ++q)
            rr[q] = *(const uint4*)(ub + (size_t)ss[q] * D + sub * 8);
#pragma unroll
        for (int q = 0; q < 4; ++q) {
            const u16* p = (const u16*)&rr[q];
            const float wv = ww[q];
#pragma unroll
            for (int i = 0; i < 8; ++i) acc[i] += wv * b2f(p[i]);
        }
    }
#pragma unroll
    for (int i = 0; i < 8; ++i) {
        acc[i] += __shfl_xor(acc[i], 16);
        acc[i] += __shfl_xor(acc[i], 32);
    }
    if (g == 0) {
        float* o = out + (size_t)d * D + sub * 8;
        float4 o0 = *(float4*)o, o1 = *(float4*)(o + 4);
        o0.x += acc[0]; o0.y += acc[1]; o0.z += acc[2]; o0.w += acc[3];
        o1.x += acc[4]; o1.y += acc[5]; o1.z += acc[6]; o1.w += acc[7];
        *(float4*)o = o0; *(float4*)(o + 4) = o1;
    }
}

extern "C" void kernel_launch(void* const* d_in, const int* in_sizes, int n_in,
                              void* d_out, int out_size, void* d_ws, size_t ws_size,
                              hipStream_t stream)
{
    const float* x  = (const float*)d_in[0];
    const int*   ei = (const int*)d_in[1];
    const float* Wq = (const float*)d_in[2];
    const float* Wk = (const float*)d_in[3];
    const float* Wv = (const float*)d_in[4];
    const float* Wg = (const float*)d_in[5];
    const float* bg = (const float*)d_in[6];
    const float* Wl = (const float*)d_in[7];
    const float* bl = (const float*)d_in[8];

    const int M = in_sizes[0] / D;
    const int E = in_sizes[1] / 2;
    const size_t NQ = (size_t)M * D;
    const int P = 512;
    const int NBG = (M + 63) / 64;

    char* base = (char*)d_ws;
    auto alloc = [&](size_t bytes) -> char* {
        char* p = base; base += (bytes + 63) & ~(size_t)63; return p;
    };
    u16*   part    = (u16*)alloc((size_t)P * D * D * 2);
    float* Graw    = (float*)alloc(D * D * 4);
    float* pcs     = (float*)alloc((size_t)P * D * 4);
    float* csx     = (float*)alloc(D * 4);
    float* dinv    = (float*)alloc((size_t)M * 4);
    float* xkq     = (float*)alloc(D * 4);
    float* biasout = (float*)alloc(D * 4);
    int*   cnt     = (int*)alloc((size_t)M * 4);
    int*   offs    = (int*)alloc((size_t)M * 4);
    int*   bsum    = (int*)alloc(64 * 4);
    int*   epos    = (int*)alloc((size_t)E * 4);
    uint32_t* cpk  = (uint32_t*)alloc((size_t)E * 4);
    u16*   Bcatb   = (u16*)alloc((size_t)384 * D * 2);
    u16*   C5b     = (u16*)alloc(D * D * 2);
    u16*   ub      = (u16*)alloc(NQ * 2);

    const u16* stripV = Bcatb;
    const u16* stripL = Bcatb + D * D;
    const u16* stripU = Bcatb + 2 * D * D;

    float* out = (float*)d_out;

    // weights + cnt/bsum zero + CSR build
    k_prep<<<dim3(385 + (M + 127) / 128), dim3(128), 0, stream>>>(Wv, Wg, bg, Wl, bl,
                                                                  Bcatb, biasout, cnt, bsum, M);
    k_hist<<<(E + 255) / 256, 256, 0, stream>>>(ei + E, cnt, epos, E);
    k_scan1<<<(M + 1023) / 1024, 1024, 0, stream>>>(cnt, offs, bsum, dinv, M);
    k_fill<<<(E + 255) / 256, 256, 0, stream>>>(ei, ei + E, epos, dinv, offs, bsum, cpk, E);

    // dense chain (Gram restructure)
    k_gram<<<P, 256, 0, stream>>>(x, part, pcs, M);
    k_redC<<<72, 256, 0, stream>>>(part, Graw, pcs, csx, P);
    k_small<<<1, 1024, 0, stream>>>(Graw, csx, Wq, Wk, stripV, xkq, C5b);
    k_dense<<<dim3(NBG, 2), 256, 0, stream>>>(x, stripU, C5b, stripL, cnt, xkq, biasout, ub, out, M);
    k_gather<<<(M + 3) / 4, 256, 0, stream>>>(offs, cnt, bsum, cpk, ub, out, M);
}

// Round 16
// 173.114 us; speedup vs baseline: 1.0908x; 1.0183x over previous
//
#include <hip/hip_runtime.h>
#include <hip/hip_fp16.h>
#include <cstdint>
#include <cstddef>

#define D 128
#define XTS 72  // padded row stride (u16) for transposed tiles: 144B = 9*16B, bank-rotating
typedef unsigned short u16;
typedef short bf16x8 __attribute__((ext_vector_type(8)));
typedef float f32x4 __attribute__((ext_vector_type(4)));

// bf16 pack/unpack (RTNE)
__device__ __forceinline__ u16 f2b(float f) {
    uint32_t u = __float_as_uint(f);
    return (u16)((u + 0x7FFFu + ((u >> 16) & 1u)) >> 16);
}
__device__ __forceinline__ float b2f(u16 b) {
    return __uint_as_float(((uint32_t)b) << 16);
}

// XOR swizzle on bf16 k-index within a [rows][128] LDS tile (16B groups)
#define SWZ(r, k) ((k) ^ (((r) & 7) << 3))

// ---------------- K0: fold weights -> bf16 strips; zero cnt + bsum ----------------
__global__ void k_prep(const float* __restrict__ Wv, const float* __restrict__ Wg,
                       const float* __restrict__ bg, const float* __restrict__ Wl,
                       const float* __restrict__ bl,
                       u16* __restrict__ Bcatb, float* __restrict__ biasout,
                       int* __restrict__ cnt, int* __restrict__ bsum, int M)
{
    const int b = blockIdx.x;
    const int t = threadIdx.x; // 128
    if (b < 384) {
        const int strip = b >> 7, n = b & 127;
        float val;
        if (strip == 0) {
            float s = 0.f;
#pragma unroll 8
            for (int m = 0; m < D; ++m) s += Wv[t * D + m] * Wl[n * D + m];
            val = s;
        } else if (strip == 1) {
            val = Wl[n * D + t];
        } else {
            float s = 0.f;
#pragma unroll 8
            for (int m = 0; m < D; ++m) s += Wl[n * D + m] * Wg[m * D + t];
            val = 0.6f * s;
        }
        Bcatb[(size_t)b * D + t] = f2b(val);
    } else if (b == 384) {
        float s = 0.f;
#pragma unroll 8
        for (int m = 0; m < D; ++m) s += bg[m] * Wl[t * D + m];
        biasout[t] = bl[t] + 0.6f * s;
        if (t < 64) bsum[t] = 0;
    } else {
        const int i = (b - 385) * 128 + t;
        if (i < M) cnt[i] = 0;
    }
}

// histogram + record within-segment position
__global__ void k_hist(const int* __restrict__ dst, int* __restrict__ cnt,
                       int* __restrict__ epos, int E)
{
    const int e = blockIdx.x * 256 + threadIdx.x;
    if (e < E) epos[e] = atomicAdd(&cnt[dst[e]], 1);
}

// ---------------- per-1024 scan (+ dinv fused); offs stays segment-local ----------------
__global__ __launch_bounds__(1024) void k_scan1(const int* __restrict__ cnt,
                                                int* __restrict__ offs,
                                                int* __restrict__ bsum,
                                                float* __restrict__ dinv, int M)
{
    __shared__ int wsum[16];
    const int t = threadIdx.x, lane = t & 63, w = t >> 6;
    const int i = blockIdx.x * 1024 + t;
    const int v = (i < M) ? cnt[i] : 0;
    if (i < M) dinv[i] = rsqrtf((float)(v + 1)); // +1 self loop
    int s = v;
    for (int off = 1; off < 64; off <<= 1) {
        int n = __shfl_up(s, off);
        if (lane >= off) s += n;
    }
    if (lane == 63) wsum[w] = s;
    __syncthreads();
    if (w == 0) {
        int ss = (lane < 16) ? wsum[lane] : 0;
        for (int off = 1; off < 16; off <<= 1) {
            int n = __shfl_up(ss, off);
            if (lane >= off) ss += n;
        }
        if (lane < 16) wsum[lane] = ss;
    }
    __syncthreads();
    const int woff = (w == 0) ? 0 : wsum[w - 1];
    if (i < M) offs[i] = woff + s - v;
    if (t == 1023) bsum[blockIdx.x] = wsum[15];
}

// fill CSR, atomic-free: pos = segprefix + offs[d] + epos[e]; payload = src | fp16(w)<<16
__global__ void k_fill(const int* __restrict__ src, const int* __restrict__ dst,
                       const int* __restrict__ epos,
                       const float* __restrict__ dinv,
                       const int* __restrict__ offs,
                       const int* __restrict__ bsum,
                       uint32_t* __restrict__ cpk, int E)
{
    __shared__ int sbcar[64];
    const int t = threadIdx.x;
    if (t < 64) {
        const int v = bsum[t];
        int s = v;
        for (int off = 1; off < 64; off <<= 1) {
            int n = __shfl_up(s, off);
            if (t >= off) s += n;
        }
        sbcar[t] = s - v; // exclusive segment prefix
    }
    __syncthreads();
    const int e = blockIdx.x * 256 + t;
    if (e < E) {
        const int s = src[e], d = dst[e];
        const int pos = sbcar[d >> 10] + offs[d] + epos[e];
        const float w = dinv[s] * dinv[d];
        const u16 hb = __half_as_ushort(__float2half(w));
        cpk[pos] = (uint32_t)(u16)s | ((uint32_t)hb << 16);
    }
}

// ---------------- K-GRAM: split-K partials of G = X^T X + colsum(X) ----------------
__global__ __launch_bounds__(256) void k_gram(const float* __restrict__ x,
                                              u16* __restrict__ part,
                                              float* __restrict__ pcs, int M)
{
    __shared__ u16 xT[D * XTS]; // xT[c][r], row stride 72
    const int t = threadIdx.x;
    const int P = (int)gridDim.x;
    const int chunk = (M + P - 1) / P;
    const int rbeg = blockIdx.x * chunk;
    const int rend = min(rbeg + chunk, M);
    const int lane = t & 63, w = t >> 6;
    const int fr = lane & 15, kg = lane >> 4;

    f32x4 acc[2][8] = {};
    float csacc = 0.f;

    for (int r0 = rbeg; r0 < rend; r0 += 64) {
#pragma unroll
        for (int p = 0; p < 8; ++p) {
            const int flat = t + 256 * p;   // 2048 float4 slots
            const int rr = flat & 63;       // row = lane within wave
            const int c4 = flat >> 6;       // col-group, fixed per wave
            const int gr = r0 + rr;
            float4 v = make_float4(0.f, 0.f, 0.f, 0.f);
            if (gr < rend) v = *(const float4*)(x + (size_t)gr * D + c4 * 4);
            u16* dst = xT + (c4 * 4) * XTS + rr;
            dst[0]       = f2b(v.x);
            dst[XTS]     = f2b(v.y);
            dst[2 * XTS] = f2b(v.z);
            dst[3 * XTS] = f2b(v.w);
        }
        __syncthreads();
#pragma unroll
        for (int ks = 0; ks < 2; ++ks) {
            const int rb = ks * 32 + kg * 8;
            bf16x8 a[2], b[8];
#pragma unroll
            for (int i = 0; i < 2; ++i) {
                const int m = w * 32 + 16 * i + fr;
                a[i] = *(const bf16x8*)(xT + m * XTS + rb);
            }
#pragma unroll
            for (int j = 0; j < 8; ++j) {
                const int n = 16 * j + fr;
                b[j] = *(const bf16x8*)(xT + n * XTS + rb);
            }
#pragma unroll
            for (int i = 0; i < 2; ++i)
#pragma unroll
                for (int j = 0; j < 8; ++j)
                    acc[i][j] = __builtin_amdgcn_mfma_f32_16x16x32_bf16(a[i], b[j], acc[i][j], 0, 0, 0);
        }
        // colsum of this tile (register-accumulated; no atomics)
        if (t < D) {
            const u16* col = xT + t * XTS;
#pragma unroll 16
            for (int r = 0; r < 64; ++r) csacc += b2f(col[r]);
        }
        __syncthreads();
    }
    u16* pp = part + (size_t)blockIdx.x * (D * D);
#pragma unroll
    for (int i = 0; i < 2; ++i)
#pragma unroll
        for (int reg = 0; reg < 4; ++reg) {
            const int m = w * 32 + 16 * i + kg * 4 + reg;
#pragma unroll
            for (int j = 0; j < 8; ++j)
                pp[(size_t)m * D + 16 * j + fr] = f2b(acc[i][j][reg]);
        }
    if (t < D) pcs[(size_t)blockIdx.x * D + t] = csacc;
}

// split-K reduce: blocks 0..63 reduce part (bf16) -> Graw; blocks 64..71 reduce pcs -> csx
__global__ void k_redC(const u16* __restrict__ part, float* __restrict__ Craw,
                       const float* __restrict__ pcs, float* __restrict__ csx, int P)
{
    if (blockIdx.x < 64) {
        const int e = blockIdx.x * 256 + threadIdx.x; // 16384
        float s0 = 0.f, s1 = 0.f, s2 = 0.f, s3 = 0.f,
              s4 = 0.f, s5 = 0.f, s6 = 0.f, s7 = 0.f;
        int p = 0;
        for (; p + 8 <= P; p += 8) {
            s0 += b2f(part[(size_t)(p + 0) * (D * D) + e]);
            s1 += b2f(part[(size_t)(p + 1) * (D * D) + e]);
            s2 += b2f(part[(size_t)(p + 2) * (D * D) + e]);
            s3 += b2f(part[(size_t)(p + 3) * (D * D) + e]);
            s4 += b2f(part[(size_t)(p + 4) * (D * D) + e]);
            s5 += b2f(part[(size_t)(p + 5) * (D * D) + e]);
            s6 += b2f(part[(size_t)(p + 6) * (D * D) + e]);
            s7 += b2f(part[(size_t)(p + 7) * (D * D) + e]);
        }
        for (; p < P; ++p) s0 += b2f(part[(size_t)p * (D * D) + e]);
        Craw[e] = ((s0 + s1) + (s2 + s3)) + ((s4 + s5) + (s6 + s7));
    } else {
        __shared__ float red[16][16];
        const int pb = blockIdx.x - 64;         // 0..7
        const int cl = threadIdx.x & 15;        // col within group
        const int sl = threadIdx.x >> 4;        // slice 0..15
        const int col = pb * 16 + cl;
        float s = 0.f;
#pragma unroll 8
        for (int p = sl; p < P; p += 16) s += pcs[(size_t)p * D + col];
        red[sl][cl] = s;
        __syncthreads();
        if (sl == 0) {
            float tot = 0.f;
#pragma unroll
            for (int i = 0; i < 16; ++i) tot += red[i][cl];
            csx[col] = tot;
        }
    }
}

// per-wave 16x64 patch of a 128x128 GEMM (16 waves cover all)
__device__ __forceinline__ void gemm16x64(const u16* __restrict__ A,
                                          const u16* __restrict__ B,
                                          f32x4 acc[4], int rw, int cw,
                                          int fr, int kg)
{
#pragma unroll
    for (int ks = 0; ks < 4; ++ks) {
        const int kb = ks * 32 + kg * 8;
        const int r = rw + fr;
        const bf16x8 a = *(const bf16x8*)(A + r * D + SWZ(r, kb));
#pragma unroll
        for (int j = 0; j < 4; ++j) {
            const int n = cw + 16 * j + fr;
            const bf16x8 b = *(const bf16x8*)(B + n * D + SWZ(n, kb));
            acc[j] = __builtin_amdgcn_mfma_f32_16x16x32_bf16(a, b, acc[j], 0, 0, 0);
        }
    }
}

// ---------------- K-SMALL: all 128x128 algebra, 1024 threads (16 waves) ----------------
__global__ __launch_bounds__(1024) void k_small(const float* __restrict__ Graw,
                                                const float* __restrict__ csx_g,
                                                const float* __restrict__ Wq,
                                                const float* __restrict__ Wk,
                                                const u16* __restrict__ stripV,
                                                float* __restrict__ xkq,
                                                u16* __restrict__ C5b)
{
    __shared__ u16 Ga[D * D]; // G A-layout -> later Wq A-layout
    __shared__ u16 Bq[D * D]; // Wq B-layout -> later Av B-layout
    __shared__ u16 Bk[D * D]; // Wk B-layout -> later (C*inv) B-layout
    __shared__ u16 T2[D * D]; // H2^T A-layout
    __shared__ float csx[D];
    __shared__ float ksum[D];
    __shared__ float trsh[32];
    __shared__ float invS;
    const int t = threadIdx.x;
    const int lane = t & 63, w = t >> 6;       // 16 waves
    const int fr = lane & 15, kg = lane >> 4;
    const int rw = (w & 7) * 16, cw = (w >> 3) * 64;

    if (t < D) csx[t] = csx_g[t];
    // stage: Ga = G (A-layout, vectorized), Bq/Bk = Wq/Wk (B-layout = transpose)
#pragma unroll
    for (int p = 0; p < 4; ++p) {
        const int e4 = t + 1024 * p;  // 4096 float4 groups
        const int e = e4 * 4;
        const int i = e >> 7, m = e & 127;
        const float4 g = *(const float4*)(Graw + e);
        u16 gb[4] = {f2b(g.x), f2b(g.y), f2b(g.z), f2b(g.w)};
        *(uint2*)(Ga + i * D + SWZ(i, m)) = *(const uint2*)gb;
        const float4 q = *(const float4*)(Wq + e);
        const float4 k = *(const float4*)(Wk + e);
        Bq[(m + 0) * D + SWZ(m + 0, i)] = f2b(q.x);
        Bq[(m + 1) * D + SWZ(m + 1, i)] = f2b(q.y);
        Bq[(m + 2) * D + SWZ(m + 2, i)] = f2b(q.z);
        Bq[(m + 3) * D + SWZ(m + 3, i)] = f2b(q.w);
        Bk[(m + 0) * D + SWZ(m + 0, i)] = f2b(k.x);
        Bk[(m + 1) * D + SWZ(m + 1, i)] = f2b(k.y);
        Bk[(m + 2) * D + SWZ(m + 2, i)] = f2b(k.z);
        Bk[(m + 3) * D + SWZ(m + 3, i)] = f2b(k.w);
    }
    __syncthreads();

    // H2 = G @ Wk -> T2 = H2^T (A-layout); trace_k
    {
        f32x4 acc[4] = {};
        gemm16x64(Ga, Bk, acc, rw, cw, fr, kg);
        float tk = 0.f;
#pragma unroll
        for (int reg = 0; reg < 4; ++reg) {
            const int row = rw + kg * 4 + reg;
#pragma unroll
            for (int j = 0; j < 4; ++j) {
                const int col = cw + 16 * j + fr;
                const float h = acc[j][reg];
                T2[col * D + SWZ(col, row)] = f2b(h);
                tk += h * b2f(Bk[col * D + SWZ(col, row)]); // Wk[row][col]
            }
        }
        for (int off = 32; off > 0; off >>= 1) tk += __shfl_down(tk, off);
        if (lane == 0) trsh[w] = tk;
    }
    __syncthreads();
    // H1 = G @ Wq -> trace_q
    {
        f32x4 acc[4] = {};
        gemm16x64(Ga, Bq, acc, rw, cw, fr, kg);
        float tq = 0.f;
#pragma unroll
        for (int reg = 0; reg < 4; ++reg) {
            const int row = rw + kg * 4 + reg;
#pragma unroll
            for (int j = 0; j < 4; ++j) {
                const int col = cw + 16 * j + fr;
                tq += acc[j][reg] * b2f(Bq[col * D + SWZ(col, row)]);
            }
        }
        for (int off = 32; off > 0; off >>= 1) tq += __shfl_down(tq, off);
        if (lane == 0) trsh[16 + w] = tq;
    }
    __syncthreads();
    if (t == 0) {
        float sk = 0.f, sq = 0.f;
#pragma unroll
        for (int i = 0; i < 16; ++i) { sk += trsh[i]; sq += trsh[16 + i]; }
        invS = 1.0f / (sqrtf(sq) * sqrtf(sk) * 128.0f);
    }
    if (t < D) {
        float s = 0.f;
#pragma unroll 8
        for (int j = 0; j < D; ++j) s += csx[j] * Wk[j * D + t];
        ksum[t] = s;
    }
    // restage: Ga <- Wq (A-layout, vectorized), Bq <- Av (B-layout, from stripV bf16)
#pragma unroll
    for (int p = 0; p < 4; ++p) {
        const int e4 = t + 1024 * p;
        const int e = e4 * 4;
        const int i = e >> 7, m = e & 127;
        const float4 q = *(const float4*)(Wq + e);
        u16 qb[4] = {f2b(q.x), f2b(q.y), f2b(q.z), f2b(q.w)};
        *(uint2*)(Ga + i * D + SWZ(i, m)) = *(const uint2*)qb;
    }
#pragma unroll
    for (int p = 0; p < 2; ++p) {
        const int e8 = (t + 1024 * p) * 8;
        const int n = e8 >> 7, i0 = e8 & 127;
        *(uint4*)(Bq + n * D + SWZ(n, i0)) = *(const uint4*)(stripV + n * D + i0);
    }
    __syncthreads();
    // C = T2(H2^T) @ Bq(Av) -> Bk <- (C*inv) B-layout; xkq
    {
        f32x4 acc[4] = {};
        gemm16x64(T2, Bq, acc, rw, cw, fr, kg);
        const float inv = invS;
#pragma unroll
        for (int reg = 0; reg < 4; ++reg) {
            const int m = rw + kg * 4 + reg;
#pragma unroll
            for (int j = 0; j < 4; ++j) {
                const int n = cw + 16 * j + fr;
                Bk[n * D + SWZ(n, m)] = f2b(acc[j][reg] * inv);
            }
        }
    }
    if (t < D) {
        float s = 0.f;
        const float inv = invS;
#pragma unroll 8
        for (int o = 0; o < D; ++o) s += Wq[t * D + o] * ksum[o];
        xkq[t] = s * inv;
    }
    __syncthreads();
    // C4 = Ga(Wq) @ Bk(C*inv); C5b[n][i] = Av[i][n] + C4[i][n]
    {
        f32x4 acc[4] = {};
        gemm16x64(Ga, Bk, acc, rw, cw, fr, kg);
#pragma unroll
        for (int reg = 0; reg < 4; ++reg) {
            const int r = rw + kg * 4 + reg; // C4 row i-index
#pragma unroll
            for (int j = 0; j < 4; ++j) {
                const int n = cw + 16 * j + fr;
                C5b[n * D + r] = f2b(b2f(stripV[n * D + r]) + acc[j][reg]);
            }
        }
    }
}

// ---------------- K-DENSE: u = x@U; out = rc*(x@C5) + 0.24*(x@Wl^T) + bias + sc*u ----------------
// grid (NBG, 2): blockIdx.y = 64-col half. Writes ub (bf16, for gather) and out.
__global__ __launch_bounds__(256) void k_dense(const float* __restrict__ x,
                                               const u16* __restrict__ stripU,
                                               const u16* __restrict__ C5b,
                                               const u16* __restrict__ stripL,
                                               const int* __restrict__ cnt,
                                               const float* __restrict__ xkq,
                                               const float* __restrict__ biasout,
                                               u16* __restrict__ ub,
                                               float* __restrict__ out, int M)
{
    __shared__ u16 As[64 * D];
    __shared__ u16 Bs[64 * D];
    __shared__ float scaleS[64];
    const int t = threadIdx.x;
    const int row0 = blockIdx.x * 64;
    const int half = blockIdx.y;

#pragma unroll
    for (int p = 0; p < 4; ++p) {
        const int flat = t + 256 * p;
        const int r = flat >> 4, kg = flat & 15;
        int gr = row0 + r; if (gr > M - 1) gr = M - 1;
        const float4 f0 = *(const float4*)(x + (size_t)gr * D + kg * 8);
        const float4 f1 = *(const float4*)(x + (size_t)gr * D + kg * 8 + 4);
        u16 rr[8] = {f2b(f0.x), f2b(f0.y), f2b(f0.z), f2b(f0.w),
                     f2b(f1.x), f2b(f1.y), f2b(f1.z), f2b(f1.w)};
        *(uint4*)(As + r * D + SWZ(r, kg * 8)) = *(const uint4*)rr;
    }
#pragma unroll
    for (int p = 0; p < 4; ++p) {
        const int flat = t + 256 * p;
        const int r = flat >> 4, kg = flat & 15;
        const uint4 v = *(const uint4*)(stripU + (size_t)(half * 64 + r) * D + kg * 8);
        *(uint4*)(Bs + r * D + SWZ(r, kg * 8)) = v;
    }
    __syncthreads();

    // rc: qk_r = x_r . xkq (redundant per half, cheap)
    {
        const int rr = t >> 2, qq = t & 3;
        float s = 0.f;
#pragma unroll
        for (int i = 0; i < 4; ++i) {
            const int kk = qq * 32 + i * 8;
            const bf16x8 a = *(const bf16x8*)(As + rr * D + SWZ(rr, kk));
            const u16* ap = (const u16*)&a;
#pragma unroll
            for (int jj = 0; jj < 8; ++jj) s += b2f(ap[jj]) * xkq[kk + jj];
        }
        s += __shfl_xor(s, 1);
        s += __shfl_xor(s, 2);
        if (qq == 0) scaleS[rr] = 0.16f / (1.0f + s);
    }

    const int lane = t & 63, w = t >> 6;
    const int wr = (w >> 1) * 32, wc = (w & 1) * 32;
    const int fr = lane & 15, kg2 = lane >> 4;

    // GEMM 1: u half
    f32x4 accU[2][2] = {};
#pragma unroll
    for (int ks = 0; ks < 4; ++ks) {
        const int kb = ks * 32 + kg2 * 8;
        bf16x8 a[2], b[2];
#pragma unroll
        for (int i = 0; i < 2; ++i) {
            const int r = wr + 16 * i + fr;
            a[i] = *(const bf16x8*)(As + r * D + SWZ(r, kb));
        }
#pragma unroll
        for (int j = 0; j < 2; ++j) {
            const int r = wc + 16 * j + fr;
            b[j] = *(const bf16x8*)(Bs + r * D + SWZ(r, kb));
        }
#pragma unroll
        for (int i = 0; i < 2; ++i)
#pragma unroll
            for (int j = 0; j < 2; ++j)
                accU[i][j] = __builtin_amdgcn_mfma_f32_16x16x32_bf16(a[i], b[j], accU[i][j], 0, 0, 0);
    }
    __syncthreads();
    // restage Bs <- C5b half
#pragma unroll
    for (int p = 0; p < 4; ++p) {
        const int flat = t + 256 * p;
        const int r = flat >> 4, kg = flat & 15;
        const uint4 v = *(const uint4*)(C5b + (size_t)(half * 64 + r) * D + kg * 8);
        *(uint4*)(Bs + r * D + SWZ(r, kg * 8)) = v;
    }
    __syncthreads();

    // GEMM 2: attention half
    f32x4 acc1[2][2] = {};
#pragma unroll
    for (int ks = 0; ks < 4; ++ks) {
        const int kb = ks * 32 + kg2 * 8;
        bf16x8 a[2], b[2];
#pragma unroll
        for (int i = 0; i < 2; ++i) {
            const int r = wr + 16 * i + fr;
            a[i] = *(const bf16x8*)(As + r * D + SWZ(r, kb));
        }
#pragma unroll
        for (int j = 0; j < 2; ++j) {
            const int r = wc + 16 * j + fr;
            b[j] = *(const bf16x8*)(Bs + r * D + SWZ(r, kb));
        }
#pragma unroll
        for (int i = 0; i < 2; ++i)
#pragma unroll
            for (int j = 0; j < 2; ++j)
                acc1[i][j] = __builtin_amdgcn_mfma_f32_16x16x32_bf16(a[i], b[j], acc1[i][j], 0, 0, 0);
    }
    __syncthreads();
    // restage Bs <- stripL half
#pragma unroll
    for (int p = 0; p < 4; ++p) {
        const int flat = t + 256 * p;
        const int r = flat >> 4, kg = flat & 15;
        const uint4 v = *(const uint4*)(stripL + (size_t)(half * 64 + r) * D + kg * 8);
        *(uint4*)(Bs + r * D + SWZ(r, kg * 8)) = v;
    }
    __syncthreads();

    // GEMM 3: xW half
    f32x4 acc2[2][2] = {};
#pragma unroll
    for (int ks = 0; ks < 4; ++ks) {
        const int kb = ks * 32 + kg2 * 8;
        bf16x8 a[2], b[2];
#pragma unroll
        for (int i = 0; i < 2; ++i) {
            const int r = wr + 16 * i + fr;
            a[i] = *(const bf16x8*)(As + r * D + SWZ(r, kb));
        }
#pragma unroll
        for (int j = 0; j < 2; ++j) {
            const int r = wc + 16 * j + fr;
            b[j] = *(const bf16x8*)(Bs + r * D + SWZ(r, kb));
        }
#pragma unroll
        for (int i = 0; i < 2; ++i)
#pragma unroll
            for (int j = 0; j < 2; ++j)
                acc2[i][j] = __builtin_amdgcn_mfma_f32_16x16x32_bf16(a[i], b[j], acc2[i][j], 0, 0, 0);
    }

    // epilogue: write ub (bf16) + out (u used in-register)
#pragma unroll
    for (int i = 0; i < 2; ++i) {
#pragma unroll
        for (int reg = 0; reg < 4; ++reg) {
            const int rloc = wr + 16 * i + kg2 * 4 + reg;
            const int r = row0 + rloc;
            if (r < M) {
                const float rc = scaleS[rloc];
                const float sc = 1.0f / (float)(cnt[r] + 1);
#pragma unroll
                for (int j = 0; j < 2; ++j) {
                    const int c = half * 64 + wc + 16 * j + fr;
                    const size_t idx = (size_t)r * D + c;
                    const float uv = accU[i][j][reg];
                    ub[idx] = f2b(uv);
                    out[idx] = rc * acc1[i][j][reg] + 0.24f * acc2[i][j][reg]
                             + biasout[c] + sc * uv;
                }
            }
        }
    }
}

// ---------------- K5: wave-cooperative CSR gather, 16 edges in flight ----------------
// out-of-range slots clamp to edge end-1 -> duplicate row read (L1-hit), w=0: exact math,
// no distinct-row waste, full 4-deep MLP preserved.
__global__ __launch_bounds__(256) void k_gather(const int* __restrict__ offs,
                                                const int* __restrict__ cnt,
                                                const int* __restrict__ bsum,
                                                const uint32_t* __restrict__ cpk,
                                                const u16* __restrict__ ub,
                                                float* __restrict__ out, int M)
{
    __shared__ int sbcar[64];
    const int t = threadIdx.x;
    if (t < 64) {
        const int v = bsum[t];
        int s = v;
        for (int off = 1; off < 64; off <<= 1) {
            int n = __shfl_up(s, off);
            if (t >= off) s += n;
        }
        sbcar[t] = s - v;
    }
    __syncthreads();
    const int w = t >> 6, lane = t & 63;
    const int d = blockIdx.x * 4 + w;
    if (d >= M) return;
    const int g = lane >> 4, sub = lane & 15;
    const int n = cnt[d];
    if (n == 0) return;
    const int beg = sbcar[d >> 10] + offs[d];
    const int end = beg + n;
    const int last = end - 1;
    float acc[8] = {};
    for (int j0 = beg; j0 < end; j0 += 16) {
        int ss[4]; float ww[4];
#pragma unroll
        for (int q = 0; q < 4; ++q) {
            const int j = j0 + 4 * q + g;
            const int jc = (j < last) ? j : last;   // clamp to last real edge
            const uint32_t p = cpk[jc];
            ss[q] = (int)(p & 0xFFFFu);
            ww[q] = (j < end) ? __half2float(__ushort_as_half((u16)(p >> 16))) : 0.f;
        }
        uint4 rr[4];
#pragma unroll
        for (int q = 0; q < 4; ++q)
            rr[q] = *(const uint4*)(ub + (size_t)ss[q] * D + sub * 8);
#pragma unroll
        for (int q = 0; q < 4; ++q) {
            const u16* p = (const u16*)&rr[q];
            const float wv = ww[q];
#pragma unroll
            for (int i = 0; i < 8; ++i) acc[i] += wv * b2f(p[i]);
        }
    }
#pragma unroll
    for (int i = 0; i < 8; ++i) {
        acc[i] += __shfl_xor(acc[i], 16);
        acc[i] += __shfl_xor(acc[i], 32);
    }
    if (g == 0) {
        float* o = out + (size_t)d * D + sub * 8;
        float4 o0 = *(float4*)o, o1 = *(float4*)(o + 4);
        o0.x += acc[0]; o0.y += acc[1]; o0.z += acc[2]; o0.w += acc[3];
        o1.x += acc[4]; o1.y += acc[5]; o1.z += acc[6]; o1.w += acc[7];
        *(float4*)o = o0; *(float4*)(o + 4) = o1;
    }
}

extern "C" void kernel_launch(void* const* d_in, const int* in_sizes, int n_in,
                              void* d_out, int out_size, void* d_ws, size_t ws_size,
                              hipStream_t stream)
{
    const float* x  = (const float*)d_in[0];
    const int*   ei = (const int*)d_in[1];
    const float* Wq = (const float*)d_in[2];
    const float* Wk = (const float*)d_in[3];
    const float* Wv = (const float*)d_in[4];
    const float* Wg = (const float*)d_in[5];
    const float* bg = (const float*)d_in[6];
    const float* Wl = (const float*)d_in[7];
    const float* bl = (const float*)d_in[8];

    const int M = in_sizes[0] / D;
    const int E = in_sizes[1] / 2;
    const size_t NQ = (size_t)M * D;
    const int P = 512;
    const int NBG = (M + 63) / 64;

    char* base = (char*)d_ws;
    auto alloc = [&](size_t bytes) -> char* {
        char* p = base; base += (bytes + 63) & ~(size_t)63; return p;
    };
    u16*   part    = (u16*)alloc((size_t)P * D * D * 2);
    float* Graw    = (float*)alloc(D * D * 4);
    float* pcs     = (float*)alloc((size_t)P * D * 4);
    float* csx     = (float*)alloc(D * 4);
    float* dinv    = (float*)alloc((size_t)M * 4);
    float* xkq     = (float*)alloc(D * 4);
    float* biasout = (float*)alloc(D * 4);
    int*   cnt     = (int*)alloc((size_t)M * 4);
    int*   offs    = (int*)alloc((size_t)M * 4);
    int*   bsum    = (int*)alloc(64 * 4);
    int*   epos    = (int*)alloc((size_t)E * 4);
    uint32_t* cpk  = (uint32_t*)alloc((size_t)E * 4);
    u16*   Bcatb   = (u16*)alloc((size_t)384 * D * 2);
    u16*   C5b     = (u16*)alloc(D * D * 2);
    u16*   ub      = (u16*)alloc(NQ * 2);

    const u16* stripV = Bcatb;
    const u16* stripL = Bcatb + D * D;
    const u16* stripU = Bcatb + 2 * D * D;

    float* out = (float*)d_out;

    // weights + cnt/bsum zero + CSR build
    k_prep<<<dim3(385 + (M + 127) / 128), dim3(128), 0, stream>>>(Wv, Wg, bg, Wl, bl,
                                                                  Bcatb, biasout, cnt, bsum, M);
    k_hist<<<(E + 255) / 256, 256, 0, stream>>>(ei + E, cnt, epos, E);
    k_scan1<<<(M + 1023) / 1024, 1024, 0, stream>>>(cnt, offs, bsum, dinv, M);
    k_fill<<<(E + 255) / 256, 256, 0, stream>>>(ei, ei + E, epos, dinv, offs, bsum, cpk, E);

    // dense chain (Gram restructure)
    k_gram<<<P, 256, 0, stream>>>(x, part, pcs, M);
    k_redC<<<72, 256, 0, stream>>>(part, Graw, pcs, csx, P);
    k_small<<<1, 1024, 0, stream>>>(Graw, csx, Wq, Wk, stripV, xkq, C5b);
    k_dense<<<dim3(NBG, 2), 256, 0, stream>>>(x, stripU, C5b, stripL, cnt, xkq, biasout, ub, out, M);
    k_gather<<<(M + 3) / 4, 256, 0, stream>>>(offs, cnt, bsum, cpk, ub, out, M);
}